// Round 16
// baseline (411.084 us; speedup 1.0000x reference)
//
#include <hip/hip_runtime.h>
#include <cstdint>
#include <cmath>

typedef unsigned int uint;
typedef unsigned short ushort;
typedef __bf16 bf16_t;
typedef bf16_t bf16x8 __attribute__((ext_vector_type(8)));
typedef float f32x4 __attribute__((ext_vector_type(4)));
typedef float f32x16 __attribute__((ext_vector_type(16)));

#define LOG2E 1.44269504088896340736f

__device__ __forceinline__ ushort f2bf(float f) {
  uint x = __float_as_uint(f);
  x += 0x7fffu + ((x >> 16) & 1u);   // RNE to bf16
  return (ushort)(x >> 16);
}
__device__ __forceinline__ uint pack2(float lo, float hi) {
  return (uint)f2bf(lo) | ((uint)f2bf(hi) << 16);
}
__device__ __forceinline__ uint cvt_pk_bf16(float lo, float hi) {
  uint r;
  asm("v_cvt_pk_bf16_f32 %0, %1, %2" : "=v"(r) : "v"(lo), "v"(hi));
  return r;
}

// global -> LDS direct copy, 16B per lane; LDS dest is wave-uniform base + lane*16.
__device__ __forceinline__ void gload_lds16(const void* gsrc, void* ldsdst) {
  typedef const __attribute__((address_space(1))) unsigned int* gp_t;
  typedef __attribute__((address_space(3))) unsigned int* lp_t;
  __builtin_amdgcn_global_load_lds((gp_t)(uintptr_t)gsrc,
                                   (lp_t)(unsigned int)(uintptr_t)ldsdst,
                                   16, 0, 0);
}

// ---------------- fp32 -> bf16 converts: x + 4 weights in ONE launch ----------------
__global__ __launch_bounds__(256) void cvt5(const float* __restrict__ x,
                                            const float* __restrict__ wq,
                                            const float* __restrict__ wk,
                                            const float* __restrict__ wv,
                                            const float* __restrict__ wo,
                                            ushort* __restrict__ xb,
                                            ushort* __restrict__ wqkv,
                                            ushort* __restrict__ wob,
                                            int nx8, int nw8) {
  const int y = blockIdx.y;
  const float* src;
  ushort* dst;
  int n8;
  if (y == 0)      { src = x;  dst = xb;  n8 = nx8; }
  else if (y == 4) { src = wo; dst = wob; n8 = nw8; }
  else {
    src = (y == 1) ? wq : (y == 2) ? wk : wv;
    dst = wqkv + (size_t)(y - 1) * nw8 * 8;
    n8 = nw8;
  }
  int i = blockIdx.x * blockDim.x + threadIdx.x;
  if (i >= n8) return;
  const float4* s4 = (const float4*)src;
  float4 a = s4[i * 2], b = s4[i * 2 + 1];
  uint4 o;
  o.x = pack2(a.x, a.y); o.y = pack2(a.z, a.w);
  o.z = pack2(b.x, b.y); o.w = pack2(b.z, b.w);
  ((uint4*)dst)[i] = o;
}

// ---------------- fused QKV GEMM: 256(M) x 192(N) tile, BK=64, 8-phase schedule ------
__global__ __launch_bounds__(512) void gemm_qkv192(const ushort* __restrict__ A,
                                                   const ushort* __restrict__ B,
                                                   const float* __restrict__ bq,
                                                   const float* __restrict__ bk,
                                                   const float* __restrict__ bv,
                                                   float* __restrict__ qpre,
                                                   float* __restrict__ kpre,
                                                   ushort* __restrict__ Vt,
                                                   int K, int S_) {
  __shared__ __align__(16) unsigned char ldsA[65536];   // [2][256 rows][64] bf16
  __shared__ __align__(16) unsigned char ldsB[49152];   // [2][192 rows][64] bf16
  const int t = threadIdx.x, l = t & 63;
  const int w = t >> 6;
  const int g = l >> 4, c = l & 15;
  const int wr = w >> 2, wc = w & 3;          // 2(M) x 4(N) wave grid
  const int tm = blockIdx.y * 256, tn = blockIdx.x * 192;

  const int srow = t >> 3;                    // 0..63
  const int schunk = (t & 7) ^ (srow & 7);    // pre-swizzled source chunk
  const ushort* Ag = A + (size_t)(tm + srow) * K + schunk * 8;
  const ushort* Bg = B + (size_t)(tn + srow) * K + schunk * 8;
  const size_t rK64 = (size_t)64 * K;

#define STG_A(kt, u) gload_lds16(Ag + (size_t)(u) * rK64 + ((kt) << 6),   \
    ldsA + ((kt)&1) * 32768 + (u) * 8192 + t * 16)
#define STG_B(kt, u) gload_lds16(Bg + (size_t)(u) * rK64 + ((kt) << 6),   \
    ldsB + ((kt)&1) * 24576 + (u) * 8192 + t * 16)

  f32x4 acc[8][3] = {};
  bf16x8 af[2][2], bfr[3][2];
  const int cr = c * 128;
  const int sw0 = ((0 * 4 + g) ^ (c & 7)) << 4;
  const int sw1 = ((1 * 4 + g) ^ (c & 7)) << 4;

#define RDA(d, q) do {                                                               \
    _Pragma("unroll") for (int mm = 0; mm < 2; ++mm) {                               \
      const unsigned char* p_ = ldsA + (d)*32768 + (wr*128 + (q)*32 + mm*16)*128 + cr; \
      af[mm][0] = *(const bf16x8*)(p_ + sw0);                                        \
      af[mm][1] = *(const bf16x8*)(p_ + sw1); }                                      \
  } while (0)
#define RDB(d) do {                                                                 \
    _Pragma("unroll") for (int nn = 0; nn < 3; ++nn) {                              \
      const unsigned char* p_ = ldsB + (d)*24576 + (wc*48 + nn*16)*128 + cr;        \
      bfr[nn][0] = *(const bf16x8*)(p_ + sw0);                                      \
      bfr[nn][1] = *(const bf16x8*)(p_ + sw1); }                                    \
  } while (0)
#define MM(q) do {                                                                  \
    __builtin_amdgcn_s_setprio(1);                                                  \
    _Pragma("unroll") for (int mm = 0; mm < 2; ++mm)                                \
    _Pragma("unroll") for (int nn = 0; nn < 3; ++nn) {                              \
      acc[(q)*2+mm][nn] = __builtin_amdgcn_mfma_f32_16x16x32_bf16(                  \
          af[mm][0], bfr[nn][0], acc[(q)*2+mm][nn], 0, 0, 0);                       \
      acc[(q)*2+mm][nn] = __builtin_amdgcn_mfma_f32_16x16x32_bf16(                  \
          af[mm][1], bfr[nn][1], acc[(q)*2+mm][nn], 0, 0, 0); }                     \
    __builtin_amdgcn_s_setprio(0);                                                  \
  } while (0)
#define BAR() __builtin_amdgcn_s_barrier()

  STG_B(0, 0); STG_B(0, 1); STG_B(0, 2);
  STG_A(0, 0); STG_A(0, 1); STG_A(0, 2); STG_A(0, 3);
  STG_B(1, 0); STG_B(1, 1); STG_B(1, 2);
  STG_A(1, 0); STG_A(1, 1); STG_A(1, 2);
  asm volatile("s_waitcnt vmcnt(6)" ::: "memory");
  BAR();

  const int NITER = K >> 7;   // 16 iterations x 2 K-tiles
  for (int i = 0; i < NITER; ++i) {
    const int k1 = 2 * i + 1, k2 = 2 * i + 2, k3 = 2 * i + 3;
    const bool st = (i + 1 < NITER);
    RDA(0, 0); RDB(0);
    STG_A(k1, 3);
    MM(0); BAR();
    RDA(0, 1);
    if (st) { STG_B(k2, 0); STG_B(k2, 1); }
    MM(1); BAR();
    RDA(0, 2);
    if (st) { STG_B(k2, 2); STG_A(k2, 0); }
    MM(2); BAR();
    RDA(0, 3);
    if (st) { STG_A(k2, 1); STG_A(k2, 2); }
    MM(3);
    if (st) asm volatile("s_waitcnt vmcnt(6)" ::: "memory");
    else    asm volatile("s_waitcnt vmcnt(0)" ::: "memory");
    BAR();
    RDA(1, 0); RDB(1);
    if (st) STG_A(k2, 3);
    MM(0); BAR();
    RDA(1, 1);
    if (st) { STG_B(k3, 0); STG_B(k3, 1); }
    MM(1); BAR();
    RDA(1, 2);
    if (st) { STG_B(k3, 2); STG_A(k3, 0); }
    MM(2); BAR();
    RDA(1, 3);
    if (st) { STG_A(k3, 1); STG_A(k3, 2); }
    MM(3);
    if (st) asm volatile("s_waitcnt vmcnt(6)" ::: "memory");
    else    asm volatile("s_waitcnt vmcnt(0)" ::: "memory");
    BAR();
  }

#undef STG_A
#undef STG_B
#undef RDA
#undef RDB
#undef MM
#undef BAR

#pragma unroll
  for (int n = 0; n < 3; ++n) {
    int col = tn + wc * 48 + n * 16 + c;
    int sel = col >> 11;
    if (sel < 2) {
      float* outp = sel ? kpre : qpre;
      const float* bias = sel ? bk : bq;
      int col2 = col & 2047;
      float bvv = bias[col2];
#pragma unroll
      for (int m = 0; m < 8; ++m) {
        int row0 = tm + wr * 128 + m * 16 + g * 4;
#pragma unroll
        for (int i = 0; i < 4; ++i)
          outp[(size_t)(row0 + i) * 2048 + col2] = acc[m][n][i] + bvv;
      }
    } else {
      int colv = col - 4096;
      float bvv = bv[colv];
#pragma unroll
      for (int m = 0; m < 8; ++m) {
        int row0 = tm + wr * 128 + m * 16 + g * 4;
        uint2 o;
        o.x = pack2(acc[m][n][0] + bvv, acc[m][n][1] + bvv);
        o.y = pack2(acc[m][n][2] + bvv, acc[m][n][3] + bvv);
        *(uint2*)(Vt + (size_t)colv * S_ + row0) = o;
      }
    }
  }
}

// ---------------- Wo GEMM: single-pass 128x128 tile, BK=64, 4-phase counted pipeline --
__global__ __launch_bounds__(512) void gemm_wo8p(const ushort* __restrict__ A,
                                                 const ushort* __restrict__ B,
                                                 const float* __restrict__ bo,
                                                 float* __restrict__ out, int K) {
  __shared__ __align__(16) unsigned char ldsA[32768];
  __shared__ __align__(16) unsigned char ldsB[32768];
  const int t = threadIdx.x, l = t & 63;
  const int w = t >> 6;
  const int g = l >> 4, c = l & 15;
  const int wr = w >> 2, wc = w & 3;
  const int tm = blockIdx.y * 128, tn = blockIdx.x * 128;

  const int srow = t >> 3;
  const int schunk = (t & 7) ^ (srow & 7);
  const ushort* Ag = A + (size_t)(tm + srow) * K + schunk * 8;
  const ushort* Bg = B + (size_t)(tn + srow) * K + schunk * 8;
  const size_t rK64 = (size_t)64 * K;

#define WSTG_A(kt, u) gload_lds16(Ag + (size_t)(u) * rK64 + ((kt) << 6),   \
    ldsA + ((kt)&1) * 16384 + (u) * 8192 + t * 16)
#define WSTG_B(kt, u) gload_lds16(Bg + (size_t)(u) * rK64 + ((kt) << 6),   \
    ldsB + ((kt)&1) * 16384 + (u) * 8192 + t * 16)

  f32x4 acc[4][2] = {};
  bf16x8 af[2][2], bfr[2][2];
  const int cr = c * 128;
  const int sw0 = ((0 * 4 + g) ^ (c & 7)) << 4;
  const int sw1 = ((1 * 4 + g) ^ (c & 7)) << 4;

#define WRDA(d, hf) do {                                                             \
    _Pragma("unroll") for (int mm = 0; mm < 2; ++mm) {                               \
      const unsigned char* p_ = ldsA + (d)*16384 + (wr*64 + ((hf)*2+mm)*16)*128 + cr; \
      af[mm][0] = *(const bf16x8*)(p_ + sw0);                                        \
      af[mm][1] = *(const bf16x8*)(p_ + sw1); }                                      \
  } while (0)
#define WRDB(d) do {                                                                \
    _Pragma("unroll") for (int nn = 0; nn < 2; ++nn) {                              \
      const unsigned char* p_ = ldsB + (d)*16384 + (wc*32 + nn*16)*128 + cr;        \
      bfr[nn][0] = *(const bf16x8*)(p_ + sw0);                                      \
      bfr[nn][1] = *(const bf16x8*)(p_ + sw1); }                                    \
  } while (0)
#define WMM(hf) do {                                                                \
    __builtin_amdgcn_s_setprio(1);                                                  \
    _Pragma("unroll") for (int mm = 0; mm < 2; ++mm)                                \
    _Pragma("unroll") for (int nn = 0; nn < 2; ++nn) {                              \
      acc[(hf)*2+mm][nn] = __builtin_amdgcn_mfma_f32_16x16x32_bf16(                 \
          af[mm][0], bfr[nn][0], acc[(hf)*2+mm][nn], 0, 0, 0);                      \
      acc[(hf)*2+mm][nn] = __builtin_amdgcn_mfma_f32_16x16x32_bf16(                 \
          af[mm][1], bfr[nn][1], acc[(hf)*2+mm][nn], 0, 0, 0); }                    \
    __builtin_amdgcn_s_setprio(0);                                                  \
  } while (0)
#define WBAR() __builtin_amdgcn_s_barrier()

  WSTG_B(0, 0); WSTG_B(0, 1); WSTG_A(0, 0); WSTG_A(0, 1);
  WSTG_B(1, 0); WSTG_B(1, 1);
  asm volatile("s_waitcnt vmcnt(2)" ::: "memory");
  WBAR();

  const int NITER = K >> 7;
  for (int i = 0; i < NITER; ++i) {
    const int k1 = 2 * i + 1, k2 = 2 * i + 2, k3 = 2 * i + 3;
    const bool st = (i + 1 < NITER);
    WRDA(0, 0); WRDB(0);
    WSTG_A(k1, 0); WSTG_A(k1, 1);
    WMM(0); WBAR();
    WRDA(0, 1);
    if (st) { WSTG_B(k2, 0); WSTG_B(k2, 1); }
    WMM(1);
    if (st) asm volatile("s_waitcnt vmcnt(2)" ::: "memory");
    else    asm volatile("s_waitcnt vmcnt(0)" ::: "memory");
    WBAR();
    WRDA(1, 0); WRDB(1);
    if (st) { WSTG_A(k2, 0); WSTG_A(k2, 1); }
    WMM(0); WBAR();
    WRDA(1, 1);
    if (st) { WSTG_B(k3, 0); WSTG_B(k3, 1); }
    WMM(1);
    if (st) asm volatile("s_waitcnt vmcnt(2)" ::: "memory");
    else    asm volatile("s_waitcnt vmcnt(0)" ::: "memory");
    WBAR();
  }

#undef WSTG_A
#undef WSTG_B
#undef WRDA
#undef WRDB
#undef WMM
#undef WBAR

#pragma unroll
  for (int n = 0; n < 2; ++n) {
    int col = tn + wc * 32 + n * 16 + c;
    float bvv = bo[col];
#pragma unroll
    for (int m = 0; m < 4; ++m) {
      int row0 = tm + wr * 64 + m * 16 + g * 4;
#pragma unroll
      for (int i = 0; i < 4; ++i)
        out[(size_t)(row0 + i) * 2048 + col] = acc[m][n][i] + bvv;
    }
  }
}

// ---------------- fused rmsnorm + 3-axis RoPE + scale-fold, fp32 -> bf16 ----------------
__global__ __launch_bounds__(256) void fuse_rms_rope(const float* __restrict__ qpre,
                                                     const float* __restrict__ kpre,
                                                     const float* __restrict__ gq,
                                                     const float* __restrict__ gk,
                                                     const float* __restrict__ fc,
                                                     const float* __restrict__ fs,
                                                     const int* __restrict__ pH,
                                                     const int* __restrict__ pW,
                                                     ushort* __restrict__ Qb,
                                                     ushort* __restrict__ Kb,
                                                     int dim, float foldq) {
  const int which = blockIdx.y;
  const float* pre = which ? kpre : qpre;
  const float* gw = which ? gk : gq;
  ushort* outp = which ? Kb : Qb;
  const float fold = which ? 1.0f : foldq;

  const int p = blockIdx.x, t = threadIdx.x;
  const float* row = pre + (size_t)p * dim;
  float v[8];
  {
    float4 a = *(const float4*)(row + t * 8);
    float4 b = *(const float4*)(row + t * 8 + 4);
    v[0] = a.x; v[1] = a.y; v[2] = a.z; v[3] = a.w;
    v[4] = b.x; v[5] = b.y; v[6] = b.z; v[7] = b.w;
  }
  float ss = 0.f;
#pragma unroll
  for (int i = 0; i < 8; ++i) ss += v[i] * v[i];
#pragma unroll
  for (int off = 32; off; off >>= 1) ss += __shfl_xor(ss, off);
  __shared__ float wsum[4];
  if ((t & 63) == 0) wsum[t >> 6] = ss;
  __syncthreads();
  float rstd = rsqrtf((wsum[0] + wsum[1] + wsum[2] + wsum[3]) * (1.0f / dim) + 1e-6f);
  float gv[8];
  {
    float4 a = *(const float4*)(gw + t * 8);
    float4 b = *(const float4*)(gw + t * 8 + 4);
    gv[0] = a.x; gv[1] = a.y; gv[2] = a.z; gv[3] = a.w;
    gv[4] = b.x; gv[5] = b.y; gv[6] = b.z; gv[7] = b.w;
  }
#pragma unroll
  for (int i = 0; i < 8; ++i) v[i] = v[i] * rstd * gv[i];

  const int H = pH[0], W = pW[0];
  const int hw = H * W;
  const int fr = p / hw;
  const int rem = p - fr * hw;
  const int hh = rem / W;
  const int ww = rem - hh * W;
  const int hd = dim / 16;
  const int cd = hd >> 1;
  const int c2 = cd / 3, c1 = cd - 2 * c2;
  const int j0 = ((t * 8) % hd) >> 1;

  uint ob[4];
#pragma unroll
  for (int q = 0; q < 4; ++q) {
    int j = j0 + q;
    int ri = (j < c1) ? fr : ((j < c1 + c2) ? hh : ww);
    float cs = fc[ri * cd + j];
    float sn = fs[ri * cd + j];
    float a = v[2 * q], b = v[2 * q + 1];
    ob[q] = pack2((a * cs - b * sn) * fold, (a * sn + b * cs) * fold);
  }
  uint4 o4; o4.x = ob[0]; o4.y = ob[1]; o4.z = ob[2]; o4.w = ob[3];
  *(uint4*)(outp + (size_t)p * dim + t * 8) = o4;
}

// ---------------- flash attention, KV split across 2 blocks (gridDim.z) ----------------
// R16: grid (16,16,2)=512 blocks, single-buffer LDS 66.5KB -> 2 blocks/CU co-resident
// (16 waves/CU, double the TLP). Each block handles half the KV tiles (its 2 ksp wave
// groups take quarters) and writes UNNORMALIZED partial U (fp32) + per-row (m*,l*).
// attn_merge combines: O = (U1 e^{m1-M} + U2 e^{m2-M}) / (l1 e^{m1-M} + l2 e^{m2-M}).
__global__ __launch_bounds__(512, 4) void attn32(const ushort* __restrict__ Qb,
                                                 const ushort* __restrict__ Kb,
                                                 const ushort* __restrict__ Vt,
                                                 float* __restrict__ pO,
                                                 float* __restrict__ pml,
                                                 const int* __restrict__ seq_lens,
                                                 int S_, int DIMc) {
  __shared__ __align__(16) unsigned char smem[66560];
  float* mlbuf = (float*)(smem + 65536);
  const int t = threadIdx.x, l = t & 63, w = t >> 6;
  const int qsub = w & 3, ksp = w >> 2;
  const int h = l >> 5, ql = l & 31;
  const int z = blockIdx.z;

  const int orig = blockIdx.y * gridDim.x + blockIdx.x;
  const int nwg = gridDim.x * gridDim.y;
  const int lin = (orig & 7) * (nwg >> 3) + (orig >> 3);
  const int q0 = (lin % gridDim.x) * 128;
  const int head = lin / gridDim.x;
  const int kvlen = seq_lens[0];

  unsigned char* sk_s = smem + ksp * 16384;
  unsigned char* sv_s = smem + 32768 + ksp * 16384;

  bf16x8 qf[8];
  {
    const ushort* qp = Qb + (size_t)(q0 + qsub * 32 + ql) * DIMc + head * 128 + h * 8;
#pragma unroll
    for (int s = 0; s < 8; ++s) qf[s] = *(const bf16x8*)(qp + s * 16);
  }

  f32x16 ofr[4] = {};
  float m_run = -1e30f, l_run = 0.f;

  const int nt = (kvlen + 63) >> 6;
  const int ntz0 = (nt + 1) >> 1;
  const int zbase = z ? ntz0 : 0;
  const int ntz = z ? (nt - ntz0) : ntz0;
  const int half = (ntz + 1) >> 1;
  const int tbase = zbase + (ksp ? half : 0);
  const int mycnt = ksp ? (ntz - half) : ((ntz < half) ? ntz : half);

  // staging invariants — ALL NAMED SCALARS (rule #20)
#define MKK(IT, KO, KD) size_t KO; uint KD;                                     \
  { int kr_ = qsub * 16 + (IT) * 4 + (l >> 4); int kc_ = (l & 15) ^ (kr_ & 15); \
    KO = (size_t)kr_ * DIMc + head * 128 + kc_ * 8;                             \
    KD = (uint)(ksp * 16384 + qsub * 4096 + (IT) * 1024 + l * 16); }
#define MKV(IT, VO, VD) size_t VO; uint VD;                                     \
  { int vr_ = qsub * 32 + (IT) * 8 + (l >> 3); int vc_ = (l & 7) ^ (vr_ & 7);   \
    VO = (size_t)(head * 128 + vr_) * S_ + vc_ * 8;                             \
    VD = (uint)(32768 + ksp * 16384 + qsub * 4096 + (IT) * 1024 + l * 16); }
  MKK(0, kO0, kD0) MKK(1, kO1, kD1) MKK(2, kO2, kD2) MKK(3, kO3, kD3)
  MKV(0, vO0, vD0) MKV(1, vO1, vD1) MKV(2, vO2, vD2) MKV(3, vO3, vD3)
#undef MKK
#undef MKV

  uint4 rk0, rk1, rk2, rk3, rv0, rv1, rv2, rv3;
  if (mycnt > 0) {
    const size_t kbq = (size_t)(tbase * 64) * DIMc;
    const int vq = tbase * 64;
    rk0 = *(const uint4*)(Kb + kO0 + kbq);
    rk1 = *(const uint4*)(Kb + kO1 + kbq);
    rk2 = *(const uint4*)(Kb + kO2 + kbq);
    rk3 = *(const uint4*)(Kb + kO3 + kbq);
    rv0 = *(const uint4*)(Vt + vO0 + vq);
    rv1 = *(const uint4*)(Vt + vO1 + vq);
    rv2 = *(const uint4*)(Vt + vO2 + vq);
    rv3 = *(const uint4*)(Vt + vO3 + vq);
  }

  for (int tt = 0; tt < half; ++tt) {
    __builtin_amdgcn_s_barrier();
    if (tt < mycnt) {
      *(uint4*)(smem + kD0) = rk0; *(uint4*)(smem + kD1) = rk1;
      *(uint4*)(smem + kD2) = rk2; *(uint4*)(smem + kD3) = rk3;
      *(uint4*)(smem + vD0) = rv0; *(uint4*)(smem + vD1) = rv1;
      *(uint4*)(smem + vD2) = rv2; *(uint4*)(smem + vD3) = rv3;
      if (tt + 1 < mycnt) {
        const size_t kbq = (size_t)((tbase + tt + 1) * 64) * DIMc;
        const int vq = (tbase + tt + 1) * 64;
        rk0 = *(const uint4*)(Kb + kO0 + kbq);
        rk1 = *(const uint4*)(Kb + kO1 + kbq);
        rk2 = *(const uint4*)(Kb + kO2 + kbq);
        rk3 = *(const uint4*)(Kb + kO3 + kbq);
        rv0 = *(const uint4*)(Vt + vO0 + vq);
        rv1 = *(const uint4*)(Vt + vO1 + vq);
        rv2 = *(const uint4*)(Vt + vO2 + vq);
        rv3 = *(const uint4*)(Vt + vO3 + vq);
      }
    }
    asm volatile("s_waitcnt lgkmcnt(0)" ::: "memory");
    __builtin_amdgcn_s_barrier();
    __builtin_amdgcn_sched_barrier(0);
    if (tt >= mycnt) continue;
    const int kv0 = (tbase + tt) * 64;

    f32x16 sfr[2] = {};
    __builtin_amdgcn_s_setprio(1);
#pragma unroll
    for (int kb = 0; kb < 2; ++kb) {
      const unsigned char* kbp = sk_s + (kb * 32 + ql) * 256;
      const int rx = (kb * 32 + ql) & 15;
#pragma unroll
      for (int s = 0; s < 8; ++s) {
        bf16x8 kf = *(const bf16x8*)(kbp + (((s * 2 + h) ^ rx) << 4));
        sfr[kb] = __builtin_amdgcn_mfma_f32_32x32x16_bf16(kf, qf[s], sfr[kb], 0, 0, 0);
      }
    }
    __builtin_amdgcn_s_setprio(0);

    if (kv0 + 64 > kvlen) {
#pragma unroll
      for (int kb = 0; kb < 2; ++kb)
#pragma unroll
        for (int r = 0; r < 16; ++r) {
          int key = kv0 + kb * 32 + (r & 3) + 8 * (r >> 2) + 4 * h;
          if (key >= kvlen) sfr[kb][r] = -1e30f;
        }
    }

    float mt = -1e30f;
#pragma unroll
    for (int kb = 0; kb < 2; ++kb)
#pragma unroll
      for (int r = 0; r < 16; ++r) mt = fmaxf(mt, sfr[kb][r]);
    mt = fmaxf(mt, __shfl_xor(mt, 32));

    if (!__all(mt <= m_run + 8.0f)) {
      float m_new = fmaxf(m_run, mt);
      float fac = __builtin_amdgcn_exp2f(m_run - m_new);
      l_run *= fac;
#pragma unroll
      for (int df = 0; df < 4; ++df) ofr[df] *= fac;
      m_run = m_new;
    }

    float ls = 0.f;
    uint u[2][4][2];
#pragma unroll
    for (int kb = 0; kb < 2; ++kb)
#pragma unroll
      for (int G = 0; G < 4; ++G) {
        float p0 = __builtin_amdgcn_exp2f(sfr[kb][G * 4 + 0] - m_run);
        float p1 = __builtin_amdgcn_exp2f(sfr[kb][G * 4 + 1] - m_run);
        float p2 = __builtin_amdgcn_exp2f(sfr[kb][G * 4 + 2] - m_run);
        float p3 = __builtin_amdgcn_exp2f(sfr[kb][G * 4 + 3] - m_run);
        ls += (p0 + p1) + (p2 + p3);
        u[kb][G][0] = cvt_pk_bf16(p0, p1);
        u[kb][G][1] = cvt_pk_bf16(p2, p3);
      }
    ls += __shfl_xor(ls, 32);
    l_run += ls;

#pragma unroll
    for (int ks = 0; ks < 4; ++ks) {
      const int kb = ks >> 1, G0 = (ks & 1) * 2;
      uint own0 = h ? u[kb][G0 + 1][0] : u[kb][G0][0];
      uint own1 = h ? u[kb][G0 + 1][1] : u[kb][G0][1];
      uint snd0 = h ? u[kb][G0][0] : u[kb][G0 + 1][0];
      uint snd1 = h ? u[kb][G0][1] : u[kb][G0 + 1][1];
      uint rcv0 = __shfl_xor(snd0, 32);
      uint rcv1 = __shfl_xor(snd1, 32);
      union { uint4 q; bf16x8 b; } uu;
      uu.q.x = h ? rcv0 : own0;
      uu.q.y = h ? rcv1 : own1;
      uu.q.z = h ? own0 : rcv0;
      uu.q.w = h ? own1 : rcv1;
      __builtin_amdgcn_s_setprio(1);
#pragma unroll
      for (int df = 0; df < 4; ++df) {
        const int row = df * 32 + ql;
        bf16x8 vf = *(const bf16x8*)(sv_s + row * 128 + (((ks * 2 + h) ^ (row & 7)) << 4));
        ofr[df] = __builtin_amdgcn_mfma_f32_32x32x16_bf16(vf, uu.b, ofr[df], 0, 0, 0);
      }
      __builtin_amdgcn_s_setprio(0);
    }
  }

  // ---- in-block merge of 2 ksp groups -> UNNORMALIZED partial + (m*, l*) ----
  __syncthreads();
  if (ksp == 1) {
    if (h == 0) { mlbuf[qsub * 64 + ql] = m_run; mlbuf[qsub * 64 + 32 + ql] = l_run; }
    float* ob = (float*)(smem + qsub * 16384);
#pragma unroll
    for (int df = 0; df < 4; ++df)
#pragma unroll
      for (int r = 0; r < 16; ++r) {
        int d = df * 32 + (r & 3) + 8 * (r >> 2) + 4 * h;
        ob[d * 32 + ql] = ofr[df][r];
      }
  }
  __syncthreads();
  if (ksp == 0) {
    const int row = q0 + qsub * 32 + ql;
    float m2 = mlbuf[qsub * 64 + ql], l2 = mlbuf[qsub * 64 + 32 + ql];
    float mstar = fmaxf(m_run, m2);
    float f1 = __builtin_amdgcn_exp2f(m_run - mstar);
    float f2 = (l2 > 0.f) ? __builtin_amdgcn_exp2f(m2 - mstar) : 0.f;
    float lstar = l_run * f1 + l2 * f2;
    if (h == 0) {
      size_t mi = ((size_t)z * 2048 + row) * 32 + head * 2;
      pml[mi] = mstar;
      pml[mi + 1] = lstar;
    }
    const float* ob = (const float*)(smem + qsub * 16384);
    float* prow = pO + (size_t)z * 4194304 + (size_t)row * 2048 + head * 128;
#pragma unroll
    for (int df = 0; df < 4; ++df)
#pragma unroll
      for (int G = 0; G < 4; ++G) {
        int d0 = df * 32 + 8 * G + 4 * h;
        float4 o;
        o.x = ofr[df][G * 4 + 0] * f1 + ob[(d0 + 0) * 32 + ql] * f2;
        o.y = ofr[df][G * 4 + 1] * f1 + ob[(d0 + 1) * 32 + ql] * f2;
        o.z = ofr[df][G * 4 + 2] * f1 + ob[(d0 + 2) * 32 + ql] * f2;
        o.w = ofr[df][G * 4 + 3] * f1 + ob[(d0 + 3) * 32 + ql] * f2;
        *(float4*)(prow + d0) = o;
      }
  }
}

// ---------------- merge the 2 KV-split partials -> Ob bf16 ----------------
__global__ __launch_bounds__(256) void attn_merge(const float* __restrict__ pO,
                                                  const float* __restrict__ pml,
                                                  ushort* __restrict__ Ob, int n4) {
  int i = blockIdx.x * 256 + threadIdx.x;
  if (i >= n4) return;
  int row = i >> 9;                 // 512 float4 per 2048-col row
  int head = (i & 511) >> 5;        // col/128 = ((i&511)*4)/128
  size_t mi = (size_t)row * 32 + head * 2;
  float m1 = pml[mi], l1 = pml[mi + 1];
  float m2 = pml[65536 + mi], l2 = pml[65536 + mi + 1];
  float M = fmaxf(m1, m2);
  float e1 = __builtin_amdgcn_exp2f(m1 - M);
  float e2 = __builtin_amdgcn_exp2f(m2 - M);
  float inv = 1.0f / (l1 * e1 + l2 * e2);
  e1 *= inv; e2 *= inv;
  float4 o1 = ((const float4*)pO)[i];
  float4 o2 = ((const float4*)pO)[i + 1048576];
  uint2 o;
  o.x = pack2(o1.x * e1 + o2.x * e2, o1.y * e1 + o2.y * e2);
  o.y = pack2(o1.z * e1 + o2.z * e2, o1.w * e1 + o2.w * e2);
  ((uint2*)Ob)[i] = o;
}

// ---------------- host ----------------
extern "C" void kernel_launch(void* const* d_in, const int* in_sizes, int n_in,
                              void* d_out, int out_size, void* d_ws, size_t ws_size,
                              hipStream_t stream) {
  const float* x  = (const float*)d_in[0];
  const float* fc = (const float*)d_in[1];
  const float* fs = (const float*)d_in[2];
  const float* Wq = (const float*)d_in[3];
  const float* bq = (const float*)d_in[4];
  const float* Wk = (const float*)d_in[5];
  const float* bk = (const float*)d_in[6];
  const float* Wv = (const float*)d_in[7];
  const float* bv = (const float*)d_in[8];
  const float* Wo = (const float*)d_in[9];
  const float* bo = (const float*)d_in[10];
  const float* gq = (const float*)d_in[11];
  const float* gk = (const float*)d_in[12];
  const int* seq  = (const int*)d_in[13];
  const int* pH   = (const int*)d_in[15];
  const int* pW   = (const int*)d_in[16];

  const int DIMc = in_sizes[4];          // 2048
  const int S_   = in_sizes[0] / DIMc;   // 2048

  char* ws = (char*)d_ws;
  const size_t MB = 1024ull * 1024ull;
  ushort* xb    = (ushort*)(ws + 0 * MB);
  ushort* Wqkvb = (ushort*)(ws + 8 * MB);    // [6144][2048] bf16 = 24 MB
  ushort* Wob   = (ushort*)(ws + 32 * MB);
  float*  qpre  = (float*)(ws + 40 * MB);    // 16 MB (dead after fuse)
  float*  kpre  = (float*)(ws + 56 * MB);    // 16 MB (dead after fuse)
  ushort* Qb    = (ushort*)(ws + 72 * MB);
  ushort* Kb    = (ushort*)(ws + 80 * MB);
  ushort* Vt    = (ushort*)(ws + 88 * MB);
  float*  pO    = (float*)(ws + 40 * MB);    // 32 MB, aliases qpre+kpre (dead)
  float*  pml   = (float*)(ws + 8 * MB);     // 0.5 MB, aliases Wqkvb (dead after qkv)
  ushort* Ob    = (ushort*)(ws + 0 * MB);    // 8 MB, aliases xb (dead after qkv)

  const int nx8 = (S_ * DIMc) / 8;
  const int nw8 = (DIMc * DIMc) / 8;
  const int nmax = (nx8 > nw8 ? nx8 : nw8);
  cvt5<<<dim3((nmax + 255) / 256, 5), 256, 0, stream>>>(x, Wq, Wk, Wv, Wo,
                                                        xb, Wqkvb, Wob, nx8, nw8);

  gemm_qkv192<<<dim3(3 * DIMc / 192, S_ / 256), 512, 0, stream>>>(
      xb, Wqkvb, bq, bk, bv, qpre, kpre, Vt, DIMc, S_);

  const float foldq = LOG2E / sqrtf((float)(DIMc / 16));
  fuse_rms_rope<<<dim3(S_, 2), 256, 0, stream>>>(qpre, kpre, gq, gk, fc, fs, pH, pW,
                                                 Qb, Kb, DIMc, foldq);

  attn32<<<dim3(S_ / 128, 16, 2), 512, 0, stream>>>(Qb, Kb, Vt, pO, pml, seq, S_, DIMc);
  attn_merge<<<(S_ * DIMc / 4 + 255) / 256, 256, 0, stream>>>(pO, pml, Ob,
                                                              S_ * DIMc / 4);

  gemm_wo8p<<<dim3(DIMc / 128, S_ / 128), 512, 0, stream>>>(Ob, Wob, bo,
                                                            (float*)d_out, DIMc);
}

// Round 17
// 172.299 us; speedup vs baseline: 2.3859x; 2.3859x over previous
//
#include <hip/hip_runtime.h>
#include <cstdint>
#include <cmath>

typedef unsigned int uint;
typedef unsigned short ushort;
typedef __bf16 bf16_t;
typedef bf16_t bf16x8 __attribute__((ext_vector_type(8)));
typedef float f32x4 __attribute__((ext_vector_type(4)));
typedef float f32x16 __attribute__((ext_vector_type(16)));

#define LOG2E 1.44269504088896340736f

__device__ __forceinline__ ushort f2bf(float f) {
  uint x = __float_as_uint(f);
  x += 0x7fffu + ((x >> 16) & 1u);   // RNE to bf16
  return (ushort)(x >> 16);
}
__device__ __forceinline__ uint pack2(float lo, float hi) {
  return (uint)f2bf(lo) | ((uint)f2bf(hi) << 16);
}
__device__ __forceinline__ uint cvt_pk_bf16(float lo, float hi) {
  uint r;
  asm("v_cvt_pk_bf16_f32 %0, %1, %2" : "=v"(r) : "v"(lo), "v"(hi));
  return r;
}

// global -> LDS direct copy, 16B per lane; LDS dest is wave-uniform base + lane*16.
__device__ __forceinline__ void gload_lds16(const void* gsrc, void* ldsdst) {
  typedef const __attribute__((address_space(1))) unsigned int* gp_t;
  typedef __attribute__((address_space(3))) unsigned int* lp_t;
  __builtin_amdgcn_global_load_lds((gp_t)(uintptr_t)gsrc,
                                   (lp_t)(unsigned int)(uintptr_t)ldsdst,
                                   16, 0, 0);
}

// ---------------- fp32 -> bf16 converts: x + 4 weights in ONE launch ----------------
__global__ __launch_bounds__(256) void cvt5(const float* __restrict__ x,
                                            const float* __restrict__ wq,
                                            const float* __restrict__ wk,
                                            const float* __restrict__ wv,
                                            const float* __restrict__ wo,
                                            ushort* __restrict__ xb,
                                            ushort* __restrict__ wqkv,
                                            ushort* __restrict__ wob,
                                            int nx8, int nw8) {
  const int y = blockIdx.y;
  const float* src;
  ushort* dst;
  int n8;
  if (y == 0)      { src = x;  dst = xb;  n8 = nx8; }
  else if (y == 4) { src = wo; dst = wob; n8 = nw8; }
  else {
    src = (y == 1) ? wq : (y == 2) ? wk : wv;
    dst = wqkv + (size_t)(y - 1) * nw8 * 8;
    n8 = nw8;
  }
  int i = blockIdx.x * blockDim.x + threadIdx.x;
  if (i >= n8) return;
  const float4* s4 = (const float4*)src;
  float4 a = s4[i * 2], b = s4[i * 2 + 1];
  uint4 o;
  o.x = pack2(a.x, a.y); o.y = pack2(a.z, a.w);
  o.z = pack2(b.x, b.y); o.w = pack2(b.z, b.w);
  ((uint4*)dst)[i] = o;
}

// ---------------- fused QKV GEMM: 256(M) x 192(N) tile, BK=64, 8-phase schedule ------
__global__ __launch_bounds__(512) void gemm_qkv192(const ushort* __restrict__ A,
                                                   const ushort* __restrict__ B,
                                                   const float* __restrict__ bq,
                                                   const float* __restrict__ bk,
                                                   const float* __restrict__ bv,
                                                   float* __restrict__ qpre,
                                                   float* __restrict__ kpre,
                                                   ushort* __restrict__ Vt,
                                                   int K, int S_) {
  __shared__ __align__(16) unsigned char ldsA[65536];   // [2][256 rows][64] bf16
  __shared__ __align__(16) unsigned char ldsB[49152];   // [2][192 rows][64] bf16
  const int t = threadIdx.x, l = t & 63;
  const int w = t >> 6;
  const int g = l >> 4, c = l & 15;
  const int wr = w >> 2, wc = w & 3;          // 2(M) x 4(N) wave grid
  const int tm = blockIdx.y * 256, tn = blockIdx.x * 192;

  const int srow = t >> 3;                    // 0..63
  const int schunk = (t & 7) ^ (srow & 7);    // pre-swizzled source chunk
  const ushort* Ag = A + (size_t)(tm + srow) * K + schunk * 8;
  const ushort* Bg = B + (size_t)(tn + srow) * K + schunk * 8;
  const size_t rK64 = (size_t)64 * K;

#define STG_A(kt, u) gload_lds16(Ag + (size_t)(u) * rK64 + ((kt) << 6),   \
    ldsA + ((kt)&1) * 32768 + (u) * 8192 + t * 16)
#define STG_B(kt, u) gload_lds16(Bg + (size_t)(u) * rK64 + ((kt) << 6),   \
    ldsB + ((kt)&1) * 24576 + (u) * 8192 + t * 16)

  f32x4 acc[8][3] = {};
  bf16x8 af[2][2], bfr[3][2];
  const int cr = c * 128;
  const int sw0 = ((0 * 4 + g) ^ (c & 7)) << 4;
  const int sw1 = ((1 * 4 + g) ^ (c & 7)) << 4;

#define RDA(d, q) do {                                                               \
    _Pragma("unroll") for (int mm = 0; mm < 2; ++mm) {                               \
      const unsigned char* p_ = ldsA + (d)*32768 + (wr*128 + (q)*32 + mm*16)*128 + cr; \
      af[mm][0] = *(const bf16x8*)(p_ + sw0);                                        \
      af[mm][1] = *(const bf16x8*)(p_ + sw1); }                                      \
  } while (0)
#define RDB(d) do {                                                                 \
    _Pragma("unroll") for (int nn = 0; nn < 3; ++nn) {                              \
      const unsigned char* p_ = ldsB + (d)*24576 + (wc*48 + nn*16)*128 + cr;        \
      bfr[nn][0] = *(const bf16x8*)(p_ + sw0);                                      \
      bfr[nn][1] = *(const bf16x8*)(p_ + sw1); }                                    \
  } while (0)
#define MM(q) do {                                                                  \
    __builtin_amdgcn_s_setprio(1);                                                  \
    _Pragma("unroll") for (int mm = 0; mm < 2; ++mm)                                \
    _Pragma("unroll") for (int nn = 0; nn < 3; ++nn) {                              \
      acc[(q)*2+mm][nn] = __builtin_amdgcn_mfma_f32_16x16x32_bf16(                  \
          af[mm][0], bfr[nn][0], acc[(q)*2+mm][nn], 0, 0, 0);                       \
      acc[(q)*2+mm][nn] = __builtin_amdgcn_mfma_f32_16x16x32_bf16(                  \
          af[mm][1], bfr[nn][1], acc[(q)*2+mm][nn], 0, 0, 0); }                     \
    __builtin_amdgcn_s_setprio(0);                                                  \
  } while (0)
#define BAR() __builtin_amdgcn_s_barrier()

  STG_B(0, 0); STG_B(0, 1); STG_B(0, 2);
  STG_A(0, 0); STG_A(0, 1); STG_A(0, 2); STG_A(0, 3);
  STG_B(1, 0); STG_B(1, 1); STG_B(1, 2);
  STG_A(1, 0); STG_A(1, 1); STG_A(1, 2);
  asm volatile("s_waitcnt vmcnt(6)" ::: "memory");
  BAR();

  const int NITER = K >> 7;   // 16 iterations x 2 K-tiles
  for (int i = 0; i < NITER; ++i) {
    const int k1 = 2 * i + 1, k2 = 2 * i + 2, k3 = 2 * i + 3;
    const bool st = (i + 1 < NITER);
    RDA(0, 0); RDB(0);
    STG_A(k1, 3);
    MM(0); BAR();
    RDA(0, 1);
    if (st) { STG_B(k2, 0); STG_B(k2, 1); }
    MM(1); BAR();
    RDA(0, 2);
    if (st) { STG_B(k2, 2); STG_A(k2, 0); }
    MM(2); BAR();
    RDA(0, 3);
    if (st) { STG_A(k2, 1); STG_A(k2, 2); }
    MM(3);
    if (st) asm volatile("s_waitcnt vmcnt(6)" ::: "memory");
    else    asm volatile("s_waitcnt vmcnt(0)" ::: "memory");
    BAR();
    RDA(1, 0); RDB(1);
    if (st) STG_A(k2, 3);
    MM(0); BAR();
    RDA(1, 1);
    if (st) { STG_B(k3, 0); STG_B(k3, 1); }
    MM(1); BAR();
    RDA(1, 2);
    if (st) { STG_B(k3, 2); STG_A(k3, 0); }
    MM(2); BAR();
    RDA(1, 3);
    if (st) { STG_A(k3, 1); STG_A(k3, 2); }
    MM(3);
    if (st) asm volatile("s_waitcnt vmcnt(6)" ::: "memory");
    else    asm volatile("s_waitcnt vmcnt(0)" ::: "memory");
    BAR();
  }

#undef STG_A
#undef STG_B
#undef RDA
#undef RDB
#undef MM
#undef BAR

#pragma unroll
  for (int n = 0; n < 3; ++n) {
    int col = tn + wc * 48 + n * 16 + c;
    int sel = col >> 11;
    if (sel < 2) {
      float* outp = sel ? kpre : qpre;
      const float* bias = sel ? bk : bq;
      int col2 = col & 2047;
      float bvv = bias[col2];
#pragma unroll
      for (int m = 0; m < 8; ++m) {
        int row0 = tm + wr * 128 + m * 16 + g * 4;
#pragma unroll
        for (int i = 0; i < 4; ++i)
          outp[(size_t)(row0 + i) * 2048 + col2] = acc[m][n][i] + bvv;
      }
    } else {
      int colv = col - 4096;
      float bvv = bv[colv];
#pragma unroll
      for (int m = 0; m < 8; ++m) {
        int row0 = tm + wr * 128 + m * 16 + g * 4;
        uint2 o;
        o.x = pack2(acc[m][n][0] + bvv, acc[m][n][1] + bvv);
        o.y = pack2(acc[m][n][2] + bvv, acc[m][n][3] + bvv);
        *(uint2*)(Vt + (size_t)colv * S_ + row0) = o;
      }
    }
  }
}

// ---------------- Wo GEMM: single-pass 128x128 tile, BK=64, 4-phase counted pipeline --
__global__ __launch_bounds__(512) void gemm_wo8p(const ushort* __restrict__ A,
                                                 const ushort* __restrict__ B,
                                                 const float* __restrict__ bo,
                                                 float* __restrict__ out, int K) {
  __shared__ __align__(16) unsigned char ldsA[32768];
  __shared__ __align__(16) unsigned char ldsB[32768];
  const int t = threadIdx.x, l = t & 63;
  const int w = t >> 6;
  const int g = l >> 4, c = l & 15;
  const int wr = w >> 2, wc = w & 3;
  const int tm = blockIdx.y * 128, tn = blockIdx.x * 128;

  const int srow = t >> 3;
  const int schunk = (t & 7) ^ (srow & 7);
  const ushort* Ag = A + (size_t)(tm + srow) * K + schunk * 8;
  const ushort* Bg = B + (size_t)(tn + srow) * K + schunk * 8;
  const size_t rK64 = (size_t)64 * K;

#define WSTG_A(kt, u) gload_lds16(Ag + (size_t)(u) * rK64 + ((kt) << 6),   \
    ldsA + ((kt)&1) * 16384 + (u) * 8192 + t * 16)
#define WSTG_B(kt, u) gload_lds16(Bg + (size_t)(u) * rK64 + ((kt) << 6),   \
    ldsB + ((kt)&1) * 16384 + (u) * 8192 + t * 16)

  f32x4 acc[4][2] = {};
  bf16x8 af[2][2], bfr[2][2];
  const int cr = c * 128;
  const int sw0 = ((0 * 4 + g) ^ (c & 7)) << 4;
  const int sw1 = ((1 * 4 + g) ^ (c & 7)) << 4;

#define WRDA(d, hf) do {                                                             \
    _Pragma("unroll") for (int mm = 0; mm < 2; ++mm) {                               \
      const unsigned char* p_ = ldsA + (d)*16384 + (wr*64 + ((hf)*2+mm)*16)*128 + cr; \
      af[mm][0] = *(const bf16x8*)(p_ + sw0);                                        \
      af[mm][1] = *(const bf16x8*)(p_ + sw1); }                                      \
  } while (0)
#define WRDB(d) do {                                                                \
    _Pragma("unroll") for (int nn = 0; nn < 2; ++nn) {                              \
      const unsigned char* p_ = ldsB + (d)*16384 + (wc*32 + nn*16)*128 + cr;        \
      bfr[nn][0] = *(const bf16x8*)(p_ + sw0);                                      \
      bfr[nn][1] = *(const bf16x8*)(p_ + sw1); }                                    \
  } while (0)
#define WMM(hf) do {                                                                \
    __builtin_amdgcn_s_setprio(1);                                                  \
    _Pragma("unroll") for (int mm = 0; mm < 2; ++mm)                                \
    _Pragma("unroll") for (int nn = 0; nn < 2; ++nn) {                              \
      acc[(hf)*2+mm][nn] = __builtin_amdgcn_mfma_f32_16x16x32_bf16(                 \
          af[mm][0], bfr[nn][0], acc[(hf)*2+mm][nn], 0, 0, 0);                      \
      acc[(hf)*2+mm][nn] = __builtin_amdgcn_mfma_f32_16x16x32_bf16(                 \
          af[mm][1], bfr[nn][1], acc[(hf)*2+mm][nn], 0, 0, 0); }                    \
    __builtin_amdgcn_s_setprio(0);                                                  \
  } while (0)
#define WBAR() __builtin_amdgcn_s_barrier()

  WSTG_B(0, 0); WSTG_B(0, 1); WSTG_A(0, 0); WSTG_A(0, 1);
  WSTG_B(1, 0); WSTG_B(1, 1);
  asm volatile("s_waitcnt vmcnt(2)" ::: "memory");
  WBAR();

  const int NITER = K >> 7;
  for (int i = 0; i < NITER; ++i) {
    const int k1 = 2 * i + 1, k2 = 2 * i + 2, k3 = 2 * i + 3;
    const bool st = (i + 1 < NITER);
    WRDA(0, 0); WRDB(0);
    WSTG_A(k1, 0); WSTG_A(k1, 1);
    WMM(0); WBAR();
    WRDA(0, 1);
    if (st) { WSTG_B(k2, 0); WSTG_B(k2, 1); }
    WMM(1);
    if (st) asm volatile("s_waitcnt vmcnt(2)" ::: "memory");
    else    asm volatile("s_waitcnt vmcnt(0)" ::: "memory");
    WBAR();
    WRDA(1, 0); WRDB(1);
    if (st) { WSTG_A(k2, 0); WSTG_A(k2, 1); }
    WMM(0); WBAR();
    WRDA(1, 1);
    if (st) { WSTG_B(k3, 0); WSTG_B(k3, 1); }
    WMM(1);
    if (st) asm volatile("s_waitcnt vmcnt(2)" ::: "memory");
    else    asm volatile("s_waitcnt vmcnt(0)" ::: "memory");
    WBAR();
  }

#undef WSTG_A
#undef WSTG_B
#undef WRDA
#undef WRDB
#undef WMM
#undef WBAR

#pragma unroll
  for (int n = 0; n < 2; ++n) {
    int col = tn + wc * 32 + n * 16 + c;
    float bvv = bo[col];
#pragma unroll
    for (int m = 0; m < 4; ++m) {
      int row0 = tm + wr * 64 + m * 16 + g * 4;
#pragma unroll
      for (int i = 0; i < 4; ++i)
        out[(size_t)(row0 + i) * 2048 + col] = acc[m][n][i] + bvv;
    }
  }
}

// ---------------- fused rmsnorm + 3-axis RoPE + scale-fold, fp32 -> bf16 ----------------
__global__ __launch_bounds__(256) void fuse_rms_rope(const float* __restrict__ qpre,
                                                     const float* __restrict__ kpre,
                                                     const float* __restrict__ gq,
                                                     const float* __restrict__ gk,
                                                     const float* __restrict__ fc,
                                                     const float* __restrict__ fs,
                                                     const int* __restrict__ pH,
                                                     const int* __restrict__ pW,
                                                     ushort* __restrict__ Qb,
                                                     ushort* __restrict__ Kb,
                                                     int dim, float foldq) {
  const int which = blockIdx.y;
  const float* pre = which ? kpre : qpre;
  const float* gw = which ? gk : gq;
  ushort* outp = which ? Kb : Qb;
  const float fold = which ? 1.0f : foldq;

  const int p = blockIdx.x, t = threadIdx.x;
  const float* row = pre + (size_t)p * dim;
  float v[8];
  {
    float4 a = *(const float4*)(row + t * 8);
    float4 b = *(const float4*)(row + t * 8 + 4);
    v[0] = a.x; v[1] = a.y; v[2] = a.z; v[3] = a.w;
    v[4] = b.x; v[5] = b.y; v[6] = b.z; v[7] = b.w;
  }
  float ss = 0.f;
#pragma unroll
  for (int i = 0; i < 8; ++i) ss += v[i] * v[i];
#pragma unroll
  for (int off = 32; off; off >>= 1) ss += __shfl_xor(ss, off);
  __shared__ float wsum[4];
  if ((t & 63) == 0) wsum[t >> 6] = ss;
  __syncthreads();
  float rstd = rsqrtf((wsum[0] + wsum[1] + wsum[2] + wsum[3]) * (1.0f / dim) + 1e-6f);
  float gv[8];
  {
    float4 a = *(const float4*)(gw + t * 8);
    float4 b = *(const float4*)(gw + t * 8 + 4);
    gv[0] = a.x; gv[1] = a.y; gv[2] = a.z; gv[3] = a.w;
    gv[4] = b.x; gv[5] = b.y; gv[6] = b.z; gv[7] = b.w;
  }
#pragma unroll
  for (int i = 0; i < 8; ++i) v[i] = v[i] * rstd * gv[i];

  const int H = pH[0], W = pW[0];
  const int hw = H * W;
  const int fr = p / hw;
  const int rem = p - fr * hw;
  const int hh = rem / W;
  const int ww = rem - hh * W;
  const int hd = dim / 16;
  const int cd = hd >> 1;
  const int c2 = cd / 3, c1 = cd - 2 * c2;
  const int j0 = ((t * 8) % hd) >> 1;

  uint ob[4];
#pragma unroll
  for (int q = 0; q < 4; ++q) {
    int j = j0 + q;
    int ri = (j < c1) ? fr : ((j < c1 + c2) ? hh : ww);
    float cs = fc[ri * cd + j];
    float sn = fs[ri * cd + j];
    float a = v[2 * q], b = v[2 * q + 1];
    ob[q] = pack2((a * cs - b * sn) * fold, (a * sn + b * cs) * fold);
  }
  uint4 o4; o4.x = ob[0]; o4.y = ob[1]; o4.z = ob[2]; o4.w = ob[3];
  *(uint4*)(outp + (size_t)p * dim + t * 8) = o4;
}

// ---------------- flash attention, KV split across 2 blocks (gridDim.z) ----------------
// R17: identical to R16 except __launch_bounds__(512, 2) — R16's (512,4) capped the
// allocator at 64 VGPR for a ~104-VGPR kernel -> scratch storm (WRITE 645 MB). At
// ~104-120 VGPR (<=128) the HW naturally co-schedules 2 blocks/CU (wave cap halves
// at VGPR 128, m69), which is the occupancy the split exists to exploit.
__global__ __launch_bounds__(512, 2) void attn32(const ushort* __restrict__ Qb,
                                                 const ushort* __restrict__ Kb,
                                                 const ushort* __restrict__ Vt,
                                                 float* __restrict__ pO,
                                                 float* __restrict__ pml,
                                                 const int* __restrict__ seq_lens,
                                                 int S_, int DIMc) {
  __shared__ __align__(16) unsigned char smem[66560];
  float* mlbuf = (float*)(smem + 65536);
  const int t = threadIdx.x, l = t & 63, w = t >> 6;
  const int qsub = w & 3, ksp = w >> 2;
  const int h = l >> 5, ql = l & 31;
  const int z = blockIdx.z;

  const int orig = blockIdx.y * gridDim.x + blockIdx.x;
  const int nwg = gridDim.x * gridDim.y;
  const int lin = (orig & 7) * (nwg >> 3) + (orig >> 3);
  const int q0 = (lin % gridDim.x) * 128;
  const int head = lin / gridDim.x;
  const int kvlen = seq_lens[0];

  unsigned char* sk_s = smem + ksp * 16384;
  unsigned char* sv_s = smem + 32768 + ksp * 16384;

  bf16x8 qf[8];
  {
    const ushort* qp = Qb + (size_t)(q0 + qsub * 32 + ql) * DIMc + head * 128 + h * 8;
#pragma unroll
    for (int s = 0; s < 8; ++s) qf[s] = *(const bf16x8*)(qp + s * 16);
  }

  f32x16 ofr[4] = {};
  float m_run = -1e30f, l_run = 0.f;

  const int nt = (kvlen + 63) >> 6;
  const int ntz0 = (nt + 1) >> 1;
  const int zbase = z ? ntz0 : 0;
  const int ntz = z ? (nt - ntz0) : ntz0;
  const int half = (ntz + 1) >> 1;
  const int tbase = zbase + (ksp ? half : 0);
  const int mycnt = ksp ? (ntz - half) : ((ntz < half) ? ntz : half);

  // staging invariants — ALL NAMED SCALARS (rule #20)
#define MKK(IT, KO, KD) size_t KO; uint KD;                                     \
  { int kr_ = qsub * 16 + (IT) * 4 + (l >> 4); int kc_ = (l & 15) ^ (kr_ & 15); \
    KO = (size_t)kr_ * DIMc + head * 128 + kc_ * 8;                             \
    KD = (uint)(ksp * 16384 + qsub * 4096 + (IT) * 1024 + l * 16); }
#define MKV(IT, VO, VD) size_t VO; uint VD;                                     \
  { int vr_ = qsub * 32 + (IT) * 8 + (l >> 3); int vc_ = (l & 7) ^ (vr_ & 7);   \
    VO = (size_t)(head * 128 + vr_) * S_ + vc_ * 8;                             \
    VD = (uint)(32768 + ksp * 16384 + qsub * 4096 + (IT) * 1024 + l * 16); }
  MKK(0, kO0, kD0) MKK(1, kO1, kD1) MKK(2, kO2, kD2) MKK(3, kO3, kD3)
  MKV(0, vO0, vD0) MKV(1, vO1, vD1) MKV(2, vO2, vD2) MKV(3, vO3, vD3)
#undef MKK
#undef MKV

  uint4 rk0, rk1, rk2, rk3, rv0, rv1, rv2, rv3;
  if (mycnt > 0) {
    const size_t kbq = (size_t)(tbase * 64) * DIMc;
    const int vq = tbase * 64;
    rk0 = *(const uint4*)(Kb + kO0 + kbq);
    rk1 = *(const uint4*)(Kb + kO1 + kbq);
    rk2 = *(const uint4*)(Kb + kO2 + kbq);
    rk3 = *(const uint4*)(Kb + kO3 + kbq);
    rv0 = *(const uint4*)(Vt + vO0 + vq);
    rv1 = *(const uint4*)(Vt + vO1 + vq);
    rv2 = *(const uint4*)(Vt + vO2 + vq);
    rv3 = *(const uint4*)(Vt + vO3 + vq);
  }

  for (int tt = 0; tt < half; ++tt) {
    __builtin_amdgcn_s_barrier();
    if (tt < mycnt) {
      *(uint4*)(smem + kD0) = rk0; *(uint4*)(smem + kD1) = rk1;
      *(uint4*)(smem + kD2) = rk2; *(uint4*)(smem + kD3) = rk3;
      *(uint4*)(smem + vD0) = rv0; *(uint4*)(smem + vD1) = rv1;
      *(uint4*)(smem + vD2) = rv2; *(uint4*)(smem + vD3) = rv3;
      if (tt + 1 < mycnt) {
        const size_t kbq = (size_t)((tbase + tt + 1) * 64) * DIMc;
        const int vq = (tbase + tt + 1) * 64;
        rk0 = *(const uint4*)(Kb + kO0 + kbq);
        rk1 = *(const uint4*)(Kb + kO1 + kbq);
        rk2 = *(const uint4*)(Kb + kO2 + kbq);
        rk3 = *(const uint4*)(Kb + kO3 + kbq);
        rv0 = *(const uint4*)(Vt + vO0 + vq);
        rv1 = *(const uint4*)(Vt + vO1 + vq);
        rv2 = *(const uint4*)(Vt + vO2 + vq);
        rv3 = *(const uint4*)(Vt + vO3 + vq);
      }
    }
    asm volatile("s_waitcnt lgkmcnt(0)" ::: "memory");
    __builtin_amdgcn_s_barrier();
    __builtin_amdgcn_sched_barrier(0);
    if (tt >= mycnt) continue;
    const int kv0 = (tbase + tt) * 64;

    f32x16 sfr[2] = {};
    __builtin_amdgcn_s_setprio(1);
#pragma unroll
    for (int kb = 0; kb < 2; ++kb) {
      const unsigned char* kbp = sk_s + (kb * 32 + ql) * 256;
      const int rx = (kb * 32 + ql) & 15;
#pragma unroll
      for (int s = 0; s < 8; ++s) {
        bf16x8 kf = *(const bf16x8*)(kbp + (((s * 2 + h) ^ rx) << 4));
        sfr[kb] = __builtin_amdgcn_mfma_f32_32x32x16_bf16(kf, qf[s], sfr[kb], 0, 0, 0);
      }
    }
    __builtin_amdgcn_s_setprio(0);

    if (kv0 + 64 > kvlen) {
#pragma unroll
      for (int kb = 0; kb < 2; ++kb)
#pragma unroll
        for (int r = 0; r < 16; ++r) {
          int key = kv0 + kb * 32 + (r & 3) + 8 * (r >> 2) + 4 * h;
          if (key >= kvlen) sfr[kb][r] = -1e30f;
        }
    }

    float mt = -1e30f;
#pragma unroll
    for (int kb = 0; kb < 2; ++kb)
#pragma unroll
      for (int r = 0; r < 16; ++r) mt = fmaxf(mt, sfr[kb][r]);
    mt = fmaxf(mt, __shfl_xor(mt, 32));

    if (!__all(mt <= m_run + 8.0f)) {
      float m_new = fmaxf(m_run, mt);
      float fac = __builtin_amdgcn_exp2f(m_run - m_new);
      l_run *= fac;
#pragma unroll
      for (int df = 0; df < 4; ++df) ofr[df] *= fac;
      m_run = m_new;
    }

    float ls = 0.f;
    uint u[2][4][2];
#pragma unroll
    for (int kb = 0; kb < 2; ++kb)
#pragma unroll
      for (int G = 0; G < 4; ++G) {
        float p0 = __builtin_amdgcn_exp2f(sfr[kb][G * 4 + 0] - m_run);
        float p1 = __builtin_amdgcn_exp2f(sfr[kb][G * 4 + 1] - m_run);
        float p2 = __builtin_amdgcn_exp2f(sfr[kb][G * 4 + 2] - m_run);
        float p3 = __builtin_amdgcn_exp2f(sfr[kb][G * 4 + 3] - m_run);
        ls += (p0 + p1) + (p2 + p3);
        u[kb][G][0] = cvt_pk_bf16(p0, p1);
        u[kb][G][1] = cvt_pk_bf16(p2, p3);
      }
    ls += __shfl_xor(ls, 32);
    l_run += ls;

#pragma unroll
    for (int ks = 0; ks < 4; ++ks) {
      const int kb = ks >> 1, G0 = (ks & 1) * 2;
      uint own0 = h ? u[kb][G0 + 1][0] : u[kb][G0][0];
      uint own1 = h ? u[kb][G0 + 1][1] : u[kb][G0][1];
      uint snd0 = h ? u[kb][G0][0] : u[kb][G0 + 1][0];
      uint snd1 = h ? u[kb][G0][1] : u[kb][G0 + 1][1];
      uint rcv0 = __shfl_xor(snd0, 32);
      uint rcv1 = __shfl_xor(snd1, 32);
      union { uint4 q; bf16x8 b; } uu;
      uu.q.x = h ? rcv0 : own0;
      uu.q.y = h ? rcv1 : own1;
      uu.q.z = h ? own0 : rcv0;
      uu.q.w = h ? own1 : rcv1;
      __builtin_amdgcn_s_setprio(1);
#pragma unroll
      for (int df = 0; df < 4; ++df) {
        const int row = df * 32 + ql;
        bf16x8 vf = *(const bf16x8*)(sv_s + row * 128 + (((ks * 2 + h) ^ (row & 7)) << 4));
        ofr[df] = __builtin_amdgcn_mfma_f32_32x32x16_bf16(vf, uu.b, ofr[df], 0, 0, 0);
      }
      __builtin_amdgcn_s_setprio(0);
    }
  }

  // ---- in-block merge of 2 ksp groups -> UNNORMALIZED partial + (m*, l*) ----
  __syncthreads();
  if (ksp == 1) {
    if (h == 0) { mlbuf[qsub * 64 + ql] = m_run; mlbuf[qsub * 64 + 32 + ql] = l_run; }
    float* ob = (float*)(smem + qsub * 16384);
#pragma unroll
    for (int df = 0; df < 4; ++df)
#pragma unroll
      for (int r = 0; r < 16; ++r) {
        int d = df * 32 + (r & 3) + 8 * (r >> 2) + 4 * h;
        ob[d * 32 + ql] = ofr[df][r];
      }
  }
  __syncthreads();
  if (ksp == 0) {
    const int row = q0 + qsub * 32 + ql;
    float m2 = mlbuf[qsub * 64 + ql], l2 = mlbuf[qsub * 64 + 32 + ql];
    float mstar = fmaxf(m_run, m2);
    float f1 = __builtin_amdgcn_exp2f(m_run - mstar);
    float f2 = (l2 > 0.f) ? __builtin_amdgcn_exp2f(m2 - mstar) : 0.f;
    float lstar = l_run * f1 + l2 * f2;
    if (h == 0) {
      size_t mi = ((size_t)z * 2048 + row) * 32 + head * 2;
      pml[mi] = mstar;
      pml[mi + 1] = lstar;
    }
    const float* ob = (const float*)(smem + qsub * 16384);
    float* prow = pO + (size_t)z * 4194304 + (size_t)row * 2048 + head * 128;
#pragma unroll
    for (int df = 0; df < 4; ++df)
#pragma unroll
      for (int G = 0; G < 4; ++G) {
        int d0 = df * 32 + 8 * G + 4 * h;
        float4 o;
        o.x = ofr[df][G * 4 + 0] * f1 + ob[(d0 + 0) * 32 + ql] * f2;
        o.y = ofr[df][G * 4 + 1] * f1 + ob[(d0 + 1) * 32 + ql] * f2;
        o.z = ofr[df][G * 4 + 2] * f1 + ob[(d0 + 2) * 32 + ql] * f2;
        o.w = ofr[df][G * 4 + 3] * f1 + ob[(d0 + 3) * 32 + ql] * f2;
        *(float4*)(prow + d0) = o;
      }
  }
}

// ---------------- merge the 2 KV-split partials -> Ob bf16 ----------------
__global__ __launch_bounds__(256) void attn_merge(const float* __restrict__ pO,
                                                  const float* __restrict__ pml,
                                                  ushort* __restrict__ Ob, int n4) {
  int i = blockIdx.x * 256 + threadIdx.x;
  if (i >= n4) return;
  int row = i >> 9;                 // 512 float4 per 2048-col row
  int head = (i & 511) >> 5;        // col/128 = ((i&511)*4)/128
  size_t mi = (size_t)row * 32 + head * 2;
  float m1 = pml[mi], l1 = pml[mi + 1];
  float m2 = pml[65536 + mi], l2 = pml[65536 + mi + 1];
  float M = fmaxf(m1, m2);
  float e1 = __builtin_amdgcn_exp2f(m1 - M);
  float e2 = __builtin_amdgcn_exp2f(m2 - M);
  float inv = 1.0f / (l1 * e1 + l2 * e2);
  e1 *= inv; e2 *= inv;
  float4 o1 = ((const float4*)pO)[i];
  float4 o2 = ((const float4*)pO)[i + 1048576];
  uint2 o;
  o.x = pack2(o1.x * e1 + o2.x * e2, o1.y * e1 + o2.y * e2);
  o.y = pack2(o1.z * e1 + o2.z * e2, o1.w * e1 + o2.w * e2);
  ((uint2*)Ob)[i] = o;
}

// ---------------- host ----------------
extern "C" void kernel_launch(void* const* d_in, const int* in_sizes, int n_in,
                              void* d_out, int out_size, void* d_ws, size_t ws_size,
                              hipStream_t stream) {
  const float* x  = (const float*)d_in[0];
  const float* fc = (const float*)d_in[1];
  const float* fs = (const float*)d_in[2];
  const float* Wq = (const float*)d_in[3];
  const float* bq = (const float*)d_in[4];
  const float* Wk = (const float*)d_in[5];
  const float* bk = (const float*)d_in[6];
  const float* Wv = (const float*)d_in[7];
  const float* bv = (const float*)d_in[8];
  const float* Wo = (const float*)d_in[9];
  const float* bo = (const float*)d_in[10];
  const float* gq = (const float*)d_in[11];
  const float* gk = (const float*)d_in[12];
  const int* seq  = (const int*)d_in[13];
  const int* pH   = (const int*)d_in[15];
  const int* pW   = (const int*)d_in[16];

  const int DIMc = in_sizes[4];          // 2048
  const int S_   = in_sizes[0] / DIMc;   // 2048

  char* ws = (char*)d_ws;
  const size_t MB = 1024ull * 1024ull;
  ushort* xb    = (ushort*)(ws + 0 * MB);
  ushort* Wqkvb = (ushort*)(ws + 8 * MB);    // [6144][2048] bf16 = 24 MB
  ushort* Wob   = (ushort*)(ws + 32 * MB);
  float*  qpre  = (float*)(ws + 40 * MB);    // 16 MB (dead after fuse)
  float*  kpre  = (float*)(ws + 56 * MB);    // 16 MB (dead after fuse)
  ushort* Qb    = (ushort*)(ws + 72 * MB);
  ushort* Kb    = (ushort*)(ws + 80 * MB);
  ushort* Vt    = (ushort*)(ws + 88 * MB);
  float*  pO    = (float*)(ws + 40 * MB);    // 32 MB, aliases qpre+kpre (dead)
  float*  pml   = (float*)(ws + 8 * MB);     // 0.5 MB, aliases Wqkvb (dead after qkv)
  ushort* Ob    = (ushort*)(ws + 0 * MB);    // 8 MB, aliases xb (dead after qkv)

  const int nx8 = (S_ * DIMc) / 8;
  const int nw8 = (DIMc * DIMc) / 8;
  const int nmax = (nx8 > nw8 ? nx8 : nw8);
  cvt5<<<dim3((nmax + 255) / 256, 5), 256, 0, stream>>>(x, Wq, Wk, Wv, Wo,
                                                        xb, Wqkvb, Wob, nx8, nw8);

  gemm_qkv192<<<dim3(3 * DIMc / 192, S_ / 256), 512, 0, stream>>>(
      xb, Wqkvb, bq, bk, bv, qpre, kpre, Vt, DIMc, S_);

  const float foldq = LOG2E / sqrtf((float)(DIMc / 16));
  fuse_rms_rope<<<dim3(S_, 2), 256, 0, stream>>>(qpre, kpre, gq, gk, fc, fs, pH, pW,
                                                 Qb, Kb, DIMc, foldq);

  attn32<<<dim3(S_ / 128, 16, 2), 512, 0, stream>>>(Qb, Kb, Vt, pO, pml, seq, S_, DIMc);
  attn_merge<<<(S_ * DIMc / 4 + 255) / 256, 256, 0, stream>>>(pO, pml, Ob,
                                                              S_ * DIMc / 4);

  gemm_wo8p<<<dim3(DIMc / 128, S_ / 128), 512, 0, stream>>>(Ob, Wob, bo,
                                                            (float*)d_out, DIMc);
}

// Round 18
// 154.782 us; speedup vs baseline: 2.6559x; 1.1132x over previous
//
#include <hip/hip_runtime.h>
#include <cstdint>
#include <cmath>

typedef unsigned int uint;
typedef unsigned short ushort;
typedef __bf16 bf16_t;
typedef bf16_t bf16x8 __attribute__((ext_vector_type(8)));
typedef float f32x4 __attribute__((ext_vector_type(4)));
typedef float f32x16 __attribute__((ext_vector_type(16)));

#define LOG2E 1.44269504088896340736f

__device__ __forceinline__ ushort f2bf(float f) {
  uint x = __float_as_uint(f);
  x += 0x7fffu + ((x >> 16) & 1u);   // RNE to bf16
  return (ushort)(x >> 16);
}
__device__ __forceinline__ uint pack2(float lo, float hi) {
  return (uint)f2bf(lo) | ((uint)f2bf(hi) << 16);
}
__device__ __forceinline__ uint cvt_pk_bf16(float lo, float hi) {
  uint r;
  asm("v_cvt_pk_bf16_f32 %0, %1, %2" : "=v"(r) : "v"(lo), "v"(hi));
  return r;
}

// global -> LDS direct copy, 16B per lane; LDS dest is wave-uniform base + lane*16.
__device__ __forceinline__ void gload_lds16(const void* gsrc, void* ldsdst) {
  typedef const __attribute__((address_space(1))) unsigned int* gp_t;
  typedef __attribute__((address_space(3))) unsigned int* lp_t;
  __builtin_amdgcn_global_load_lds((gp_t)(uintptr_t)gsrc,
                                   (lp_t)(unsigned int)(uintptr_t)ldsdst,
                                   16, 0, 0);
}

// ---------------- fp32 -> bf16 converts: x + 4 weights in ONE launch ----------------
__global__ __launch_bounds__(256) void cvt5(const float* __restrict__ x,
                                            const float* __restrict__ wq,
                                            const float* __restrict__ wk,
                                            const float* __restrict__ wv,
                                            const float* __restrict__ wo,
                                            ushort* __restrict__ xb,
                                            ushort* __restrict__ wqkv,
                                            ushort* __restrict__ wob,
                                            int nx8, int nw8) {
  const int y = blockIdx.y;
  const float* src;
  ushort* dst;
  int n8;
  if (y == 0)      { src = x;  dst = xb;  n8 = nx8; }
  else if (y == 4) { src = wo; dst = wob; n8 = nw8; }
  else {
    src = (y == 1) ? wq : (y == 2) ? wk : wv;
    dst = wqkv + (size_t)(y - 1) * nw8 * 8;
    n8 = nw8;
  }
  int i = blockIdx.x * blockDim.x + threadIdx.x;
  if (i >= n8) return;
  const float4* s4 = (const float4*)src;
  float4 a = s4[i * 2], b = s4[i * 2 + 1];
  uint4 o;
  o.x = pack2(a.x, a.y); o.y = pack2(a.z, a.w);
  o.z = pack2(b.x, b.y); o.w = pack2(b.z, b.w);
  ((uint4*)dst)[i] = o;
}

// ---------------- fused QKV GEMM: 256(M) x 192(N) tile, BK=64, 8-phase schedule ------
// Grid (32,8) = 256 blocks = 1 block/CU; counted vmcnt(6) at P4/P8 (T3+T4+T5).
__global__ __launch_bounds__(512) void gemm_qkv192(const ushort* __restrict__ A,
                                                   const ushort* __restrict__ B,
                                                   const float* __restrict__ bq,
                                                   const float* __restrict__ bk,
                                                   const float* __restrict__ bv,
                                                   float* __restrict__ qpre,
                                                   float* __restrict__ kpre,
                                                   ushort* __restrict__ Vt,
                                                   int K, int S_) {
  __shared__ __align__(16) unsigned char ldsA[65536];   // [2][256 rows][64] bf16
  __shared__ __align__(16) unsigned char ldsB[49152];   // [2][192 rows][64] bf16
  const int t = threadIdx.x, l = t & 63;
  const int w = t >> 6;
  const int g = l >> 4, c = l & 15;
  const int wr = w >> 2, wc = w & 3;          // 2(M) x 4(N) wave grid
  const int tm = blockIdx.y * 256, tn = blockIdx.x * 192;

  const int srow = t >> 3;                    // 0..63
  const int schunk = (t & 7) ^ (srow & 7);    // pre-swizzled source chunk
  const ushort* Ag = A + (size_t)(tm + srow) * K + schunk * 8;
  const ushort* Bg = B + (size_t)(tn + srow) * K + schunk * 8;
  const size_t rK64 = (size_t)64 * K;

#define STG_A(kt, u) gload_lds16(Ag + (size_t)(u) * rK64 + ((kt) << 6),   \
    ldsA + ((kt)&1) * 32768 + (u) * 8192 + t * 16)
#define STG_B(kt, u) gload_lds16(Bg + (size_t)(u) * rK64 + ((kt) << 6),   \
    ldsB + ((kt)&1) * 24576 + (u) * 8192 + t * 16)

  f32x4 acc[8][3] = {};
  bf16x8 af[2][2], bfr[3][2];
  const int cr = c * 128;
  const int sw0 = ((0 * 4 + g) ^ (c & 7)) << 4;
  const int sw1 = ((1 * 4 + g) ^ (c & 7)) << 4;

#define RDA(d, q) do {                                                               \
    _Pragma("unroll") for (int mm = 0; mm < 2; ++mm) {                               \
      const unsigned char* p_ = ldsA + (d)*32768 + (wr*128 + (q)*32 + mm*16)*128 + cr; \
      af[mm][0] = *(const bf16x8*)(p_ + sw0);                                        \
      af[mm][1] = *(const bf16x8*)(p_ + sw1); }                                      \
  } while (0)
#define RDB(d) do {                                                                 \
    _Pragma("unroll") for (int nn = 0; nn < 3; ++nn) {                              \
      const unsigned char* p_ = ldsB + (d)*24576 + (wc*48 + nn*16)*128 + cr;        \
      bfr[nn][0] = *(const bf16x8*)(p_ + sw0);                                      \
      bfr[nn][1] = *(const bf16x8*)(p_ + sw1); }                                    \
  } while (0)
#define MM(q) do {                                                                  \
    __builtin_amdgcn_s_setprio(1);                                                  \
    _Pragma("unroll") for (int mm = 0; mm < 2; ++mm)                                \
    _Pragma("unroll") for (int nn = 0; nn < 3; ++nn) {                              \
      acc[(q)*2+mm][nn] = __builtin_amdgcn_mfma_f32_16x16x32_bf16(                  \
          af[mm][0], bfr[nn][0], acc[(q)*2+mm][nn], 0, 0, 0);                       \
      acc[(q)*2+mm][nn] = __builtin_amdgcn_mfma_f32_16x16x32_bf16(                  \
          af[mm][1], bfr[nn][1], acc[(q)*2+mm][nn], 0, 0, 0); }                     \
    __builtin_amdgcn_s_setprio(0);                                                  \
  } while (0)
#define BAR() __builtin_amdgcn_s_barrier()

  STG_B(0, 0); STG_B(0, 1); STG_B(0, 2);
  STG_A(0, 0); STG_A(0, 1); STG_A(0, 2); STG_A(0, 3);
  STG_B(1, 0); STG_B(1, 1); STG_B(1, 2);
  STG_A(1, 0); STG_A(1, 1); STG_A(1, 2);
  asm volatile("s_waitcnt vmcnt(6)" ::: "memory");
  BAR();

  const int NITER = K >> 7;   // 16 iterations x 2 K-tiles
  for (int i = 0; i < NITER; ++i) {
    const int k1 = 2 * i + 1, k2 = 2 * i + 2, k3 = 2 * i + 3;
    const bool st = (i + 1 < NITER);
    RDA(0, 0); RDB(0);
    STG_A(k1, 3);
    MM(0); BAR();
    RDA(0, 1);
    if (st) { STG_B(k2, 0); STG_B(k2, 1); }
    MM(1); BAR();
    RDA(0, 2);
    if (st) { STG_B(k2, 2); STG_A(k2, 0); }
    MM(2); BAR();
    RDA(0, 3);
    if (st) { STG_A(k2, 1); STG_A(k2, 2); }
    MM(3);
    if (st) asm volatile("s_waitcnt vmcnt(6)" ::: "memory");
    else    asm volatile("s_waitcnt vmcnt(0)" ::: "memory");
    BAR();
    RDA(1, 0); RDB(1);
    if (st) STG_A(k2, 3);
    MM(0); BAR();
    RDA(1, 1);
    if (st) { STG_B(k3, 0); STG_B(k3, 1); }
    MM(1); BAR();
    RDA(1, 2);
    if (st) { STG_B(k3, 2); STG_A(k3, 0); }
    MM(2); BAR();
    RDA(1, 3);
    if (st) { STG_A(k3, 1); STG_A(k3, 2); }
    MM(3);
    if (st) asm volatile("s_waitcnt vmcnt(6)" ::: "memory");
    else    asm volatile("s_waitcnt vmcnt(0)" ::: "memory");
    BAR();
  }

#undef STG_A
#undef STG_B
#undef RDA
#undef RDB
#undef MM
#undef BAR

#pragma unroll
  for (int n = 0; n < 3; ++n) {
    int col = tn + wc * 48 + n * 16 + c;
    int sel = col >> 11;
    if (sel < 2) {
      float* outp = sel ? kpre : qpre;
      const float* bias = sel ? bk : bq;
      int col2 = col & 2047;
      float bvv = bias[col2];
#pragma unroll
      for (int m = 0; m < 8; ++m) {
        int row0 = tm + wr * 128 + m * 16 + g * 4;
#pragma unroll
        for (int i = 0; i < 4; ++i)
          outp[(size_t)(row0 + i) * 2048 + col2] = acc[m][n][i] + bvv;
      }
    } else {
      int colv = col - 4096;
      float bvv = bv[colv];
#pragma unroll
      for (int m = 0; m < 8; ++m) {
        int row0 = tm + wr * 128 + m * 16 + g * 4;
        uint2 o;
        o.x = pack2(acc[m][n][0] + bvv, acc[m][n][1] + bvv);
        o.y = pack2(acc[m][n][2] + bvv, acc[m][n][3] + bvv);
        *(uint2*)(Vt + (size_t)colv * S_ + row0) = o;
      }
    }
  }
}

// ---------------- Wo GEMM: single-pass 128x128 tile, BK=64, 4-phase counted pipeline --
// Grid (16,16) = 256 blocks = 1 block/CU; writes fp32 d_out directly with bias.
__global__ __launch_bounds__(512) void gemm_wo8p(const ushort* __restrict__ A,
                                                 const ushort* __restrict__ B,
                                                 const float* __restrict__ bo,
                                                 float* __restrict__ out, int K) {
  __shared__ __align__(16) unsigned char ldsA[32768];
  __shared__ __align__(16) unsigned char ldsB[32768];
  const int t = threadIdx.x, l = t & 63;
  const int w = t >> 6;
  const int g = l >> 4, c = l & 15;
  const int wr = w >> 2, wc = w & 3;
  const int tm = blockIdx.y * 128, tn = blockIdx.x * 128;

  const int srow = t >> 3;
  const int schunk = (t & 7) ^ (srow & 7);
  const ushort* Ag = A + (size_t)(tm + srow) * K + schunk * 8;
  const ushort* Bg = B + (size_t)(tn + srow) * K + schunk * 8;
  const size_t rK64 = (size_t)64 * K;

#define WSTG_A(kt, u) gload_lds16(Ag + (size_t)(u) * rK64 + ((kt) << 6),   \
    ldsA + ((kt)&1) * 16384 + (u) * 8192 + t * 16)
#define WSTG_B(kt, u) gload_lds16(Bg + (size_t)(u) * rK64 + ((kt) << 6),   \
    ldsB + ((kt)&1) * 16384 + (u) * 8192 + t * 16)

  f32x4 acc[4][2] = {};
  bf16x8 af[2][2], bfr[2][2];
  const int cr = c * 128;
  const int sw0 = ((0 * 4 + g) ^ (c & 7)) << 4;
  const int sw1 = ((1 * 4 + g) ^ (c & 7)) << 4;

#define WRDA(d, hf) do {                                                             \
    _Pragma("unroll") for (int mm = 0; mm < 2; ++mm) {                               \
      const unsigned char* p_ = ldsA + (d)*16384 + (wr*64 + ((hf)*2+mm)*16)*128 + cr; \
      af[mm][0] = *(const bf16x8*)(p_ + sw0);                                        \
      af[mm][1] = *(const bf16x8*)(p_ + sw1); }                                      \
  } while (0)
#define WRDB(d) do {                                                                \
    _Pragma("unroll") for (int nn = 0; nn < 2; ++nn) {                              \
      const unsigned char* p_ = ldsB + (d)*16384 + (wc*32 + nn*16)*128 + cr;        \
      bfr[nn][0] = *(const bf16x8*)(p_ + sw0);                                      \
      bfr[nn][1] = *(const bf16x8*)(p_ + sw1); }                                    \
  } while (0)
#define WMM(hf) do {                                                                \
    __builtin_amdgcn_s_setprio(1);                                                  \
    _Pragma("unroll") for (int mm = 0; mm < 2; ++mm)                                \
    _Pragma("unroll") for (int nn = 0; nn < 2; ++nn) {                              \
      acc[(hf)*2+mm][nn] = __builtin_amdgcn_mfma_f32_16x16x32_bf16(                 \
          af[mm][0], bfr[nn][0], acc[(hf)*2+mm][nn], 0, 0, 0);                      \
      acc[(hf)*2+mm][nn] = __builtin_amdgcn_mfma_f32_16x16x32_bf16(                 \
          af[mm][1], bfr[nn][1], acc[(hf)*2+mm][nn], 0, 0, 0); }                    \
    __builtin_amdgcn_s_setprio(0);                                                  \
  } while (0)
#define WBAR() __builtin_amdgcn_s_barrier()

  WSTG_B(0, 0); WSTG_B(0, 1); WSTG_A(0, 0); WSTG_A(0, 1);
  WSTG_B(1, 0); WSTG_B(1, 1);
  asm volatile("s_waitcnt vmcnt(2)" ::: "memory");
  WBAR();

  const int NITER = K >> 7;
  for (int i = 0; i < NITER; ++i) {
    const int k1 = 2 * i + 1, k2 = 2 * i + 2, k3 = 2 * i + 3;
    const bool st = (i + 1 < NITER);
    WRDA(0, 0); WRDB(0);
    WSTG_A(k1, 0); WSTG_A(k1, 1);
    WMM(0); WBAR();
    WRDA(0, 1);
    if (st) { WSTG_B(k2, 0); WSTG_B(k2, 1); }
    WMM(1);
    if (st) asm volatile("s_waitcnt vmcnt(2)" ::: "memory");
    else    asm volatile("s_waitcnt vmcnt(0)" ::: "memory");
    WBAR();
    WRDA(1, 0); WRDB(1);
    if (st) { WSTG_A(k2, 0); WSTG_A(k2, 1); }
    WMM(0); WBAR();
    WRDA(1, 1);
    if (st) { WSTG_B(k3, 0); WSTG_B(k3, 1); }
    WMM(1);
    if (st) asm volatile("s_waitcnt vmcnt(2)" ::: "memory");
    else    asm volatile("s_waitcnt vmcnt(0)" ::: "memory");
    WBAR();
  }

#undef WSTG_A
#undef WSTG_B
#undef WRDA
#undef WRDB
#undef WMM
#undef WBAR

#pragma unroll
  for (int n = 0; n < 2; ++n) {
    int col = tn + wc * 32 + n * 16 + c;
    float bvv = bo[col];
#pragma unroll
    for (int m = 0; m < 4; ++m) {
      int row0 = tm + wr * 64 + m * 16 + g * 4;
#pragma unroll
      for (int i = 0; i < 4; ++i)
        out[(size_t)(row0 + i) * 2048 + col] = acc[m][n][i] + bvv;
    }
  }
}

// ---------------- fused rmsnorm + 3-axis RoPE + scale-fold, fp32 -> bf16 ----------------
__global__ __launch_bounds__(256) void fuse_rms_rope(const float* __restrict__ qpre,
                                                     const float* __restrict__ kpre,
                                                     const float* __restrict__ gq,
                                                     const float* __restrict__ gk,
                                                     const float* __restrict__ fc,
                                                     const float* __restrict__ fs,
                                                     const int* __restrict__ pH,
                                                     const int* __restrict__ pW,
                                                     ushort* __restrict__ Qb,
                                                     ushort* __restrict__ Kb,
                                                     int dim, float foldq) {
  const int which = blockIdx.y;
  const float* pre = which ? kpre : qpre;
  const float* gw = which ? gk : gq;
  ushort* outp = which ? Kb : Qb;
  const float fold = which ? 1.0f : foldq;

  const int p = blockIdx.x, t = threadIdx.x;
  const float* row = pre + (size_t)p * dim;
  float v[8];
  {
    float4 a = *(const float4*)(row + t * 8);
    float4 b = *(const float4*)(row + t * 8 + 4);
    v[0] = a.x; v[1] = a.y; v[2] = a.z; v[3] = a.w;
    v[4] = b.x; v[5] = b.y; v[6] = b.z; v[7] = b.w;
  }
  float ss = 0.f;
#pragma unroll
  for (int i = 0; i < 8; ++i) ss += v[i] * v[i];
#pragma unroll
  for (int off = 32; off; off >>= 1) ss += __shfl_xor(ss, off);
  __shared__ float wsum[4];
  if ((t & 63) == 0) wsum[t >> 6] = ss;
  __syncthreads();
  float rstd = rsqrtf((wsum[0] + wsum[1] + wsum[2] + wsum[3]) * (1.0f / dim) + 1e-6f);
  float gv[8];
  {
    float4 a = *(const float4*)(gw + t * 8);
    float4 b = *(const float4*)(gw + t * 8 + 4);
    gv[0] = a.x; gv[1] = a.y; gv[2] = a.z; gv[3] = a.w;
    gv[4] = b.x; gv[5] = b.y; gv[6] = b.z; gv[7] = b.w;
  }
#pragma unroll
  for (int i = 0; i < 8; ++i) v[i] = v[i] * rstd * gv[i];

  const int H = pH[0], W = pW[0];
  const int hw = H * W;
  const int fr = p / hw;
  const int rem = p - fr * hw;
  const int hh = rem / W;
  const int ww = rem - hh * W;
  const int hd = dim / 16;
  const int cd = hd >> 1;
  const int c2 = cd / 3, c1 = cd - 2 * c2;
  const int j0 = ((t * 8) % hd) >> 1;

  uint ob[4];
#pragma unroll
  for (int q = 0; q < 4; ++q) {
    int j = j0 + q;
    int ri = (j < c1) ? fr : ((j < c1 + c2) ? hh : ww);
    float cs = fc[ri * cd + j];
    float sn = fs[ri * cd + j];
    float a = v[2 * q], b = v[2 * q + 1];
    ob[q] = pack2((a * cs - b * sn) * fold, (a * sn + b * cs) * fold);
  }
  uint4 o4; o4.x = ob[0]; o4.y = ob[1]; o4.z = ob[2]; o4.w = ob[3];
  *(uint4*)(outp + (size_t)p * dim + t * 8) = o4;
}

// ---------------- flash attention, 32x32 MFMA, 4 q-subtiles x 2 KV-splits ----------------
// (R13/R14 proven config: T14 async-STAGE split with NAMED registers, full KV per block)
__global__ __launch_bounds__(512, 2) void attn32(const ushort* __restrict__ Qb,
                                                 const ushort* __restrict__ Kb,
                                                 const ushort* __restrict__ Vt,
                                                 ushort* __restrict__ Ob,
                                                 const int* __restrict__ seq_lens,
                                                 int S_, int DIMc) {
  __shared__ __align__(16) unsigned char smem[66560];
  float* mlbuf = (float*)(smem + 65536);
  const int t = threadIdx.x, l = t & 63, w = t >> 6;
  const int qsub = w & 3, ksp = w >> 2;
  const int h = l >> 5, ql = l & 31;

  const int orig = blockIdx.y * gridDim.x + blockIdx.x;
  const int nwg = gridDim.x * gridDim.y;
  const int lin = (orig & 7) * (nwg >> 3) + (orig >> 3);
  const int q0 = (lin % gridDim.x) * 128;
  const int head = lin / gridDim.x;
  const int kvlen = seq_lens[0];

  unsigned char* sk_s = smem + ksp * 16384;
  unsigned char* sv_s = smem + 32768 + ksp * 16384;

  bf16x8 qf[8];
  {
    const ushort* qp = Qb + (size_t)(q0 + qsub * 32 + ql) * DIMc + head * 128 + h * 8;
#pragma unroll
    for (int s = 0; s < 8; ++s) qf[s] = *(const bf16x8*)(qp + s * 16);
  }

  f32x16 ofr[4] = {};
  float m_run = -1e30f, l_run = 0.f;

  const int nt = (kvlen + 63) >> 6;
  const int half = (nt + 1) >> 1;
  const int tbase = ksp ? half : 0;
  const int mycnt = ksp ? (nt - half) : half;

  // staging invariants — ALL NAMED SCALARS (no arrays -> no scratch, rule #20)
#define MKK(IT, KO, KD) size_t KO; uint KD;                                     \
  { int kr_ = qsub * 16 + (IT) * 4 + (l >> 4); int kc_ = (l & 15) ^ (kr_ & 15); \
    KO = (size_t)kr_ * DIMc + head * 128 + kc_ * 8;                             \
    KD = (uint)(ksp * 16384 + qsub * 4096 + (IT) * 1024 + l * 16); }
#define MKV(IT, VO, VD) size_t VO; uint VD;                                     \
  { int vr_ = qsub * 32 + (IT) * 8 + (l >> 3); int vc_ = (l & 7) ^ (vr_ & 7);   \
    VO = (size_t)(head * 128 + vr_) * S_ + vc_ * 8;                             \
    VD = (uint)(32768 + ksp * 16384 + qsub * 4096 + (IT) * 1024 + l * 16); }
  MKK(0, kO0, kD0) MKK(1, kO1, kD1) MKK(2, kO2, kD2) MKK(3, kO3, kD3)
  MKV(0, vO0, vD0) MKV(1, vO1, vD1) MKV(2, vO2, vD2) MKV(3, vO3, vD3)
#undef MKK
#undef MKV

  uint4 rk0, rk1, rk2, rk3, rv0, rv1, rv2, rv3;
  if (mycnt > 0) {
    const size_t kbq = (size_t)(tbase * 64) * DIMc;
    const int vq = tbase * 64;
    rk0 = *(const uint4*)(Kb + kO0 + kbq);
    rk1 = *(const uint4*)(Kb + kO1 + kbq);
    rk2 = *(const uint4*)(Kb + kO2 + kbq);
    rk3 = *(const uint4*)(Kb + kO3 + kbq);
    rv0 = *(const uint4*)(Vt + vO0 + vq);
    rv1 = *(const uint4*)(Vt + vO1 + vq);
    rv2 = *(const uint4*)(Vt + vO2 + vq);
    rv3 = *(const uint4*)(Vt + vO3 + vq);
  }

  for (int tt = 0; tt < half; ++tt) {
    __builtin_amdgcn_s_barrier();            // prev compute done -> LDS free
    if (tt < mycnt) {
      *(uint4*)(smem + kD0) = rk0; *(uint4*)(smem + kD1) = rk1;
      *(uint4*)(smem + kD2) = rk2; *(uint4*)(smem + kD3) = rk3;
      *(uint4*)(smem + vD0) = rv0; *(uint4*)(smem + vD1) = rv1;
      *(uint4*)(smem + vD2) = rv2; *(uint4*)(smem + vD3) = rv3;
      if (tt + 1 < mycnt) {
        const size_t kbq = (size_t)((tbase + tt + 1) * 64) * DIMc;
        const int vq = (tbase + tt + 1) * 64;
        rk0 = *(const uint4*)(Kb + kO0 + kbq);
        rk1 = *(const uint4*)(Kb + kO1 + kbq);
        rk2 = *(const uint4*)(Kb + kO2 + kbq);
        rk3 = *(const uint4*)(Kb + kO3 + kbq);
        rv0 = *(const uint4*)(Vt + vO0 + vq);
        rv1 = *(const uint4*)(Vt + vO1 + vq);
        rv2 = *(const uint4*)(Vt + vO2 + vq);
        rv3 = *(const uint4*)(Vt + vO3 + vq);
      }
    }
    asm volatile("s_waitcnt lgkmcnt(0)" ::: "memory");   // my ds_writes done
    __builtin_amdgcn_s_barrier();                        // all writes visible
    __builtin_amdgcn_sched_barrier(0);                   // rule #18 fence
    if (tt >= mycnt) continue;
    const int kv0 = (tbase + tt) * 64;

    f32x16 sfr[2] = {};
    __builtin_amdgcn_s_setprio(1);
#pragma unroll
    for (int kb = 0; kb < 2; ++kb) {
      const unsigned char* kbp = sk_s + (kb * 32 + ql) * 256;
      const int rx = (kb * 32 + ql) & 15;
#pragma unroll
      for (int s = 0; s < 8; ++s) {
        bf16x8 kf = *(const bf16x8*)(kbp + (((s * 2 + h) ^ rx) << 4));
        sfr[kb] = __builtin_amdgcn_mfma_f32_32x32x16_bf16(kf, qf[s], sfr[kb], 0, 0, 0);
      }
    }
    __builtin_amdgcn_s_setprio(0);

    if (kv0 + 64 > kvlen) {
#pragma unroll
      for (int kb = 0; kb < 2; ++kb)
#pragma unroll
        for (int r = 0; r < 16; ++r) {
          int key = kv0 + kb * 32 + (r & 3) + 8 * (r >> 2) + 4 * h;
          if (key >= kvlen) sfr[kb][r] = -1e30f;
        }
    }

    float mt = -1e30f;
#pragma unroll
    for (int kb = 0; kb < 2; ++kb)
#pragma unroll
      for (int r = 0; r < 16; ++r) mt = fmaxf(mt, sfr[kb][r]);
    mt = fmaxf(mt, __shfl_xor(mt, 32));

    if (!__all(mt <= m_run + 8.0f)) {
      float m_new = fmaxf(m_run, mt);
      float fac = __builtin_amdgcn_exp2f(m_run - m_new);
      l_run *= fac;
#pragma unroll
      for (int df = 0; df < 4; ++df) ofr[df] *= fac;
      m_run = m_new;
    }

    float ls = 0.f;
    uint u[2][4][2];
#pragma unroll
    for (int kb = 0; kb < 2; ++kb)
#pragma unroll
      for (int G = 0; G < 4; ++G) {
        float p0 = __builtin_amdgcn_exp2f(sfr[kb][G * 4 + 0] - m_run);
        float p1 = __builtin_amdgcn_exp2f(sfr[kb][G * 4 + 1] - m_run);
        float p2 = __builtin_amdgcn_exp2f(sfr[kb][G * 4 + 2] - m_run);
        float p3 = __builtin_amdgcn_exp2f(sfr[kb][G * 4 + 3] - m_run);
        ls += (p0 + p1) + (p2 + p3);
        u[kb][G][0] = cvt_pk_bf16(p0, p1);
        u[kb][G][1] = cvt_pk_bf16(p2, p3);
      }
    ls += __shfl_xor(ls, 32);
    l_run += ls;

#pragma unroll
    for (int ks = 0; ks < 4; ++ks) {
      const int kb = ks >> 1, G0 = (ks & 1) * 2;
      uint own0 = h ? u[kb][G0 + 1][0] : u[kb][G0][0];
      uint own1 = h ? u[kb][G0 + 1][1] : u[kb][G0][1];
      uint snd0 = h ? u[kb][G0][0] : u[kb][G0 + 1][0];
      uint snd1 = h ? u[kb][G0][1] : u[kb][G0 + 1][1];
      uint rcv0 = __shfl_xor(snd0, 32);
      uint rcv1 = __shfl_xor(snd1, 32);
      union { uint4 q; bf16x8 b; } uu;
      uu.q.x = h ? rcv0 : own0;
      uu.q.y = h ? rcv1 : own1;
      uu.q.z = h ? own0 : rcv0;
      uu.q.w = h ? own1 : rcv1;
      __builtin_amdgcn_s_setprio(1);
#pragma unroll
      for (int df = 0; df < 4; ++df) {
        const int row = df * 32 + ql;
        bf16x8 vf = *(const bf16x8*)(sv_s + row * 128 + (((ks * 2 + h) ^ (row & 7)) << 4));
        ofr[df] = __builtin_amdgcn_mfma_f32_32x32x16_bf16(vf, uu.b, ofr[df], 0, 0, 0);
      }
      __builtin_amdgcn_s_setprio(0);
    }
  }

  __syncthreads();
  if (ksp == 1) {
    if (h == 0) { mlbuf[qsub * 64 + ql] = m_run; mlbuf[qsub * 64 + 32 + ql] = l_run; }
    float* ob = (float*)(smem + qsub * 16384);
#pragma unroll
    for (int df = 0; df < 4; ++df)
#pragma unroll
      for (int r = 0; r < 16; ++r) {
        int d = df * 32 + (r & 3) + 8 * (r >> 2) + 4 * h;
        ob[d * 32 + ql] = ofr[df][r];
      }
  }
  __syncthreads();
  if (ksp == 0) {
    float m2 = mlbuf[qsub * 64 + ql], l2 = mlbuf[qsub * 64 + 32 + ql];
    float mstar = fmaxf(m_run, m2);
    float f1 = __builtin_amdgcn_exp2f(m_run - mstar);
    float f2 = (l2 > 0.f) ? __builtin_amdgcn_exp2f(m2 - mstar) : 0.f;
    float lstar = l_run * f1 + l2 * f2;
    float inv = 1.0f / lstar;
    float a1 = f1 * inv, a2 = f2 * inv;
    const float* ob = (const float*)(smem + qsub * 16384);
    ushort* orow = Ob + (size_t)(q0 + qsub * 32 + ql) * DIMc + head * 128;
#pragma unroll
    for (int df = 0; df < 4; ++df)
#pragma unroll
      for (int G = 0; G < 4; ++G) {
        int d0 = df * 32 + 8 * G + 4 * h;
        float v0 = ofr[df][G * 4 + 0] * a1 + ob[(d0 + 0) * 32 + ql] * a2;
        float v1 = ofr[df][G * 4 + 1] * a1 + ob[(d0 + 1) * 32 + ql] * a2;
        float v2 = ofr[df][G * 4 + 2] * a1 + ob[(d0 + 2) * 32 + ql] * a2;
        float v3 = ofr[df][G * 4 + 3] * a1 + ob[(d0 + 3) * 32 + ql] * a2;
        uint2 o; o.x = pack2(v0, v1); o.y = pack2(v2, v3);
        *(uint2*)(orow + d0) = o;
      }
  }
}

// ---------------- host ----------------
extern "C" void kernel_launch(void* const* d_in, const int* in_sizes, int n_in,
                              void* d_out, int out_size, void* d_ws, size_t ws_size,
                              hipStream_t stream) {
  const float* x  = (const float*)d_in[0];
  const float* fc = (const float*)d_in[1];
  const float* fs = (const float*)d_in[2];
  const float* Wq = (const float*)d_in[3];
  const float* bq = (const float*)d_in[4];
  const float* Wk = (const float*)d_in[5];
  const float* bk = (const float*)d_in[6];
  const float* Wv = (const float*)d_in[7];
  const float* bv = (const float*)d_in[8];
  const float* Wo = (const float*)d_in[9];
  const float* bo = (const float*)d_in[10];
  const float* gq = (const float*)d_in[11];
  const float* gk = (const float*)d_in[12];
  const int* seq  = (const int*)d_in[13];
  const int* pH   = (const int*)d_in[15];
  const int* pW   = (const int*)d_in[16];

  const int DIMc = in_sizes[4];          // 2048
  const int S_   = in_sizes[0] / DIMc;   // 2048

  char* ws = (char*)d_ws;
  const size_t MB = 1024ull * 1024ull;
  ushort* xb    = (ushort*)(ws + 0 * MB);
  ushort* Wqkvb = (ushort*)(ws + 8 * MB);    // [6144][2048] bf16 = 24 MB
  ushort* Wob   = (ushort*)(ws + 32 * MB);
  float*  qpre  = (float*)(ws + 40 * MB);    // 16 MB
  float*  kpre  = (float*)(ws + 56 * MB);    // 16 MB
  ushort* Qb    = (ushort*)(ws + 72 * MB);
  ushort* Kb    = (ushort*)(ws + 80 * MB);
  ushort* Vt    = (ushort*)(ws + 88 * MB);
  ushort* Ob    = (ushort*)(ws + 40 * MB);   // aliases qpre (dead after fuse)

  const int nx8 = (S_ * DIMc) / 8;
  const int nw8 = (DIMc * DIMc) / 8;
  const int nmax = (nx8 > nw8 ? nx8 : nw8);
  cvt5<<<dim3((nmax + 255) / 256, 5), 256, 0, stream>>>(x, Wq, Wk, Wv, Wo,
                                                        xb, Wqkvb, Wob, nx8, nw8);

  gemm_qkv192<<<dim3(3 * DIMc / 192, S_ / 256), 512, 0, stream>>>(
      xb, Wqkvb, bq, bk, bv, qpre, kpre, Vt, DIMc, S_);

  const float foldq = LOG2E / sqrtf((float)(DIMc / 16));
  fuse_rms_rope<<<dim3(S_, 2), 256, 0, stream>>>(qpre, kpre, gq, gk, fc, fs, pH, pW,
                                                 Qb, Kb, DIMc, foldq);

  attn32<<<dim3(S_ / 128, 16), 512, 0, stream>>>(Qb, Kb, Vt, Ob, seq, S_, DIMc);

  gemm_wo8p<<<dim3(DIMc / 128, S_ / 128), 512, 0, stream>>>(Ob, Wob, bo,
                                                            (float*)d_out, DIMc);
}

// Round 19
// 153.673 us; speedup vs baseline: 2.6751x; 1.0072x over previous
//
#include <hip/hip_runtime.h>
#include <cstdint>
#include <cmath>

typedef unsigned int uint;
typedef unsigned short ushort;
typedef __bf16 bf16_t;
typedef bf16_t bf16x8 __attribute__((ext_vector_type(8)));
typedef float f32x4 __attribute__((ext_vector_type(4)));
typedef float f32x16 __attribute__((ext_vector_type(16)));

#define LOG2E 1.44269504088896340736f

__device__ __forceinline__ ushort f2bf(float f) {
  uint x = __float_as_uint(f);
  x += 0x7fffu + ((x >> 16) & 1u);   // RNE to bf16
  return (ushort)(x >> 16);
}
__device__ __forceinline__ uint pack2(float lo, float hi) {
  return (uint)f2bf(lo) | ((uint)f2bf(hi) << 16);
}
__device__ __forceinline__ uint cvt_pk_bf16(float lo, float hi) {
  uint r;
  asm("v_cvt_pk_bf16_f32 %0, %1, %2" : "=v"(r) : "v"(lo), "v"(hi));
  return r;
}

// global -> LDS direct copy, 16B per lane; LDS dest is wave-uniform base + lane*16.
__device__ __forceinline__ void gload_lds16(const void* gsrc, void* ldsdst) {
  typedef const __attribute__((address_space(1))) unsigned int* gp_t;
  typedef __attribute__((address_space(3))) unsigned int* lp_t;
  __builtin_amdgcn_global_load_lds((gp_t)(uintptr_t)gsrc,
                                   (lp_t)(unsigned int)(uintptr_t)ldsdst,
                                   16, 0, 0);
}

// ---------------- fp32 -> bf16 converts: x + 4 weights in ONE launch ----------------
__global__ __launch_bounds__(256) void cvt5(const float* __restrict__ x,
                                            const float* __restrict__ wq,
                                            const float* __restrict__ wk,
                                            const float* __restrict__ wv,
                                            const float* __restrict__ wo,
                                            ushort* __restrict__ xb,
                                            ushort* __restrict__ wqkv,
                                            ushort* __restrict__ wob,
                                            int nx8, int nw8) {
  const int y = blockIdx.y;
  const float* src;
  ushort* dst;
  int n8;
  if (y == 0)      { src = x;  dst = xb;  n8 = nx8; }
  else if (y == 4) { src = wo; dst = wob; n8 = nw8; }
  else {
    src = (y == 1) ? wq : (y == 2) ? wk : wv;
    dst = wqkv + (size_t)(y - 1) * nw8 * 8;
    n8 = nw8;
  }
  int i = blockIdx.x * blockDim.x + threadIdx.x;
  if (i >= n8) return;
  const float4* s4 = (const float4*)src;
  float4 a = s4[i * 2], b = s4[i * 2 + 1];
  uint4 o;
  o.x = pack2(a.x, a.y); o.y = pack2(a.z, a.w);
  o.z = pack2(b.x, b.y); o.w = pack2(b.z, b.w);
  ((uint4*)dst)[i] = o;
}

// ---------------- fused QKV GEMM: 256(M) x 192(N) tile, BK=64, 8-phase schedule ------
// Grid (32,8) = 256 blocks = 1 block/CU; counted vmcnt(6) at P4/P8 (T3+T4+T5).
// R19: q/k pre-activations written as BF16 (halves the qpre/kpre interchange traffic;
// fuse_rms_rope rounds to bf16 after normalization anyway, so added error ~0.1-0.2%).
__global__ __launch_bounds__(512) void gemm_qkv192(const ushort* __restrict__ A,
                                                   const ushort* __restrict__ B,
                                                   const float* __restrict__ bq,
                                                   const float* __restrict__ bk,
                                                   const float* __restrict__ bv,
                                                   ushort* __restrict__ qpre,
                                                   ushort* __restrict__ kpre,
                                                   ushort* __restrict__ Vt,
                                                   int K, int S_) {
  __shared__ __align__(16) unsigned char ldsA[65536];   // [2][256 rows][64] bf16
  __shared__ __align__(16) unsigned char ldsB[49152];   // [2][192 rows][64] bf16
  const int t = threadIdx.x, l = t & 63;
  const int w = t >> 6;
  const int g = l >> 4, c = l & 15;
  const int wr = w >> 2, wc = w & 3;          // 2(M) x 4(N) wave grid
  const int tm = blockIdx.y * 256, tn = blockIdx.x * 192;

  const int srow = t >> 3;                    // 0..63
  const int schunk = (t & 7) ^ (srow & 7);    // pre-swizzled source chunk
  const ushort* Ag = A + (size_t)(tm + srow) * K + schunk * 8;
  const ushort* Bg = B + (size_t)(tn + srow) * K + schunk * 8;
  const size_t rK64 = (size_t)64 * K;

#define STG_A(kt, u) gload_lds16(Ag + (size_t)(u) * rK64 + ((kt) << 6),   \
    ldsA + ((kt)&1) * 32768 + (u) * 8192 + t * 16)
#define STG_B(kt, u) gload_lds16(Bg + (size_t)(u) * rK64 + ((kt) << 6),   \
    ldsB + ((kt)&1) * 24576 + (u) * 8192 + t * 16)

  f32x4 acc[8][3] = {};
  bf16x8 af[2][2], bfr[3][2];
  const int cr = c * 128;
  const int sw0 = ((0 * 4 + g) ^ (c & 7)) << 4;
  const int sw1 = ((1 * 4 + g) ^ (c & 7)) << 4;

#define RDA(d, q) do {                                                               \
    _Pragma("unroll") for (int mm = 0; mm < 2; ++mm) {                               \
      const unsigned char* p_ = ldsA + (d)*32768 + (wr*128 + (q)*32 + mm*16)*128 + cr; \
      af[mm][0] = *(const bf16x8*)(p_ + sw0);                                        \
      af[mm][1] = *(const bf16x8*)(p_ + sw1); }                                      \
  } while (0)
#define RDB(d) do {                                                                 \
    _Pragma("unroll") for (int nn = 0; nn < 3; ++nn) {                              \
      const unsigned char* p_ = ldsB + (d)*24576 + (wc*48 + nn*16)*128 + cr;        \
      bfr[nn][0] = *(const bf16x8*)(p_ + sw0);                                      \
      bfr[nn][1] = *(const bf16x8*)(p_ + sw1); }                                    \
  } while (0)
#define MM(q) do {                                                                  \
    __builtin_amdgcn_s_setprio(1);                                                  \
    _Pragma("unroll") for (int mm = 0; mm < 2; ++mm)                                \
    _Pragma("unroll") for (int nn = 0; nn < 3; ++nn) {                              \
      acc[(q)*2+mm][nn] = __builtin_amdgcn_mfma_f32_16x16x32_bf16(                  \
          af[mm][0], bfr[nn][0], acc[(q)*2+mm][nn], 0, 0, 0);                       \
      acc[(q)*2+mm][nn] = __builtin_amdgcn_mfma_f32_16x16x32_bf16(                  \
          af[mm][1], bfr[nn][1], acc[(q)*2+mm][nn], 0, 0, 0); }                     \
    __builtin_amdgcn_s_setprio(0);                                                  \
  } while (0)
#define BAR() __builtin_amdgcn_s_barrier()

  STG_B(0, 0); STG_B(0, 1); STG_B(0, 2);
  STG_A(0, 0); STG_A(0, 1); STG_A(0, 2); STG_A(0, 3);
  STG_B(1, 0); STG_B(1, 1); STG_B(1, 2);
  STG_A(1, 0); STG_A(1, 1); STG_A(1, 2);
  asm volatile("s_waitcnt vmcnt(6)" ::: "memory");
  BAR();

  const int NITER = K >> 7;   // 16 iterations x 2 K-tiles
  for (int i = 0; i < NITER; ++i) {
    const int k1 = 2 * i + 1, k2 = 2 * i + 2, k3 = 2 * i + 3;
    const bool st = (i + 1 < NITER);
    RDA(0, 0); RDB(0);
    STG_A(k1, 3);
    MM(0); BAR();
    RDA(0, 1);
    if (st) { STG_B(k2, 0); STG_B(k2, 1); }
    MM(1); BAR();
    RDA(0, 2);
    if (st) { STG_B(k2, 2); STG_A(k2, 0); }
    MM(2); BAR();
    RDA(0, 3);
    if (st) { STG_A(k2, 1); STG_A(k2, 2); }
    MM(3);
    if (st) asm volatile("s_waitcnt vmcnt(6)" ::: "memory");
    else    asm volatile("s_waitcnt vmcnt(0)" ::: "memory");
    BAR();
    RDA(1, 0); RDB(1);
    if (st) STG_A(k2, 3);
    MM(0); BAR();
    RDA(1, 1);
    if (st) { STG_B(k3, 0); STG_B(k3, 1); }
    MM(1); BAR();
    RDA(1, 2);
    if (st) { STG_B(k3, 2); STG_A(k3, 0); }
    MM(2); BAR();
    RDA(1, 3);
    if (st) { STG_A(k3, 1); STG_A(k3, 2); }
    MM(3);
    if (st) asm volatile("s_waitcnt vmcnt(6)" ::: "memory");
    else    asm volatile("s_waitcnt vmcnt(0)" ::: "memory");
    BAR();
  }

#undef STG_A
#undef STG_B
#undef RDA
#undef RDB
#undef MM
#undef BAR

#pragma unroll
  for (int n = 0; n < 3; ++n) {
    int col = tn + wc * 48 + n * 16 + c;
    int sel = col >> 11;
    if (sel < 2) {
      ushort* outp = sel ? kpre : qpre;
      const float* bias = sel ? bk : bq;
      int col2 = col & 2047;
      float bvv = bias[col2];
#pragma unroll
      for (int m = 0; m < 8; ++m) {
        int row0 = tm + wr * 128 + m * 16 + g * 4;
#pragma unroll
        for (int i = 0; i < 4; ++i)
          outp[(size_t)(row0 + i) * 2048 + col2] = f2bf(acc[m][n][i] + bvv);
      }
    } else {
      int colv = col - 4096;
      float bvv = bv[colv];
#pragma unroll
      for (int m = 0; m < 8; ++m) {
        int row0 = tm + wr * 128 + m * 16 + g * 4;
        uint2 o;
        o.x = pack2(acc[m][n][0] + bvv, acc[m][n][1] + bvv);
        o.y = pack2(acc[m][n][2] + bvv, acc[m][n][3] + bvv);
        *(uint2*)(Vt + (size_t)colv * S_ + row0) = o;
      }
    }
  }
}

// ---------------- Wo GEMM: single-pass 128x128 tile, BK=64, 4-phase counted pipeline --
__global__ __launch_bounds__(512) void gemm_wo8p(const ushort* __restrict__ A,
                                                 const ushort* __restrict__ B,
                                                 const float* __restrict__ bo,
                                                 float* __restrict__ out, int K) {
  __shared__ __align__(16) unsigned char ldsA[32768];
  __shared__ __align__(16) unsigned char ldsB[32768];
  const int t = threadIdx.x, l = t & 63;
  const int w = t >> 6;
  const int g = l >> 4, c = l & 15;
  const int wr = w >> 2, wc = w & 3;
  const int tm = blockIdx.y * 128, tn = blockIdx.x * 128;

  const int srow = t >> 3;
  const int schunk = (t & 7) ^ (srow & 7);
  const ushort* Ag = A + (size_t)(tm + srow) * K + schunk * 8;
  const ushort* Bg = B + (size_t)(tn + srow) * K + schunk * 8;
  const size_t rK64 = (size_t)64 * K;

#define WSTG_A(kt, u) gload_lds16(Ag + (size_t)(u) * rK64 + ((kt) << 6),   \
    ldsA + ((kt)&1) * 16384 + (u) * 8192 + t * 16)
#define WSTG_B(kt, u) gload_lds16(Bg + (size_t)(u) * rK64 + ((kt) << 6),   \
    ldsB + ((kt)&1) * 16384 + (u) * 8192 + t * 16)

  f32x4 acc[4][2] = {};
  bf16x8 af[2][2], bfr[2][2];
  const int cr = c * 128;
  const int sw0 = ((0 * 4 + g) ^ (c & 7)) << 4;
  const int sw1 = ((1 * 4 + g) ^ (c & 7)) << 4;

#define WRDA(d, hf) do {                                                             \
    _Pragma("unroll") for (int mm = 0; mm < 2; ++mm) {                               \
      const unsigned char* p_ = ldsA + (d)*16384 + (wr*64 + ((hf)*2+mm)*16)*128 + cr; \
      af[mm][0] = *(const bf16x8*)(p_ + sw0);                                        \
      af[mm][1] = *(const bf16x8*)(p_ + sw1); }                                      \
  } while (0)
#define WRDB(d) do {                                                                \
    _Pragma("unroll") for (int nn = 0; nn < 2; ++nn) {                              \
      const unsigned char* p_ = ldsB + (d)*16384 + (wc*32 + nn*16)*128 + cr;        \
      bfr[nn][0] = *(const bf16x8*)(p_ + sw0);                                      \
      bfr[nn][1] = *(const bf16x8*)(p_ + sw1); }                                    \
  } while (0)
#define WMM(hf) do {                                                                \
    __builtin_amdgcn_s_setprio(1);                                                  \
    _Pragma("unroll") for (int mm = 0; mm < 2; ++mm)                                \
    _Pragma("unroll") for (int nn = 0; nn < 2; ++nn) {                              \
      acc[(hf)*2+mm][nn] = __builtin_amdgcn_mfma_f32_16x16x32_bf16(                 \
          af[mm][0], bfr[nn][0], acc[(hf)*2+mm][nn], 0, 0, 0);                      \
      acc[(hf)*2+mm][nn] = __builtin_amdgcn_mfma_f32_16x16x32_bf16(                 \
          af[mm][1], bfr[nn][1], acc[(hf)*2+mm][nn], 0, 0, 0); }                    \
    __builtin_amdgcn_s_setprio(0);                                                  \
  } while (0)
#define WBAR() __builtin_amdgcn_s_barrier()

  WSTG_B(0, 0); WSTG_B(0, 1); WSTG_A(0, 0); WSTG_A(0, 1);
  WSTG_B(1, 0); WSTG_B(1, 1);
  asm volatile("s_waitcnt vmcnt(2)" ::: "memory");
  WBAR();

  const int NITER = K >> 7;
  for (int i = 0; i < NITER; ++i) {
    const int k1 = 2 * i + 1, k2 = 2 * i + 2, k3 = 2 * i + 3;
    const bool st = (i + 1 < NITER);
    WRDA(0, 0); WRDB(0);
    WSTG_A(k1, 0); WSTG_A(k1, 1);
    WMM(0); WBAR();
    WRDA(0, 1);
    if (st) { WSTG_B(k2, 0); WSTG_B(k2, 1); }
    WMM(1);
    if (st) asm volatile("s_waitcnt vmcnt(2)" ::: "memory");
    else    asm volatile("s_waitcnt vmcnt(0)" ::: "memory");
    WBAR();
    WRDA(1, 0); WRDB(1);
    if (st) { WSTG_A(k2, 0); WSTG_A(k2, 1); }
    WMM(0); WBAR();
    WRDA(1, 1);
    if (st) { WSTG_B(k3, 0); WSTG_B(k3, 1); }
    WMM(1);
    if (st) asm volatile("s_waitcnt vmcnt(2)" ::: "memory");
    else    asm volatile("s_waitcnt vmcnt(0)" ::: "memory");
    WBAR();
  }

#undef WSTG_A
#undef WSTG_B
#undef WRDA
#undef WRDB
#undef WMM
#undef WBAR

#pragma unroll
  for (int n = 0; n < 2; ++n) {
    int col = tn + wc * 32 + n * 16 + c;
    float bvv = bo[col];
#pragma unroll
    for (int m = 0; m < 4; ++m) {
      int row0 = tm + wr * 64 + m * 16 + g * 4;
#pragma unroll
      for (int i = 0; i < 4; ++i)
        out[(size_t)(row0 + i) * 2048 + col] = acc[m][n][i] + bvv;
    }
  }
}

// ---------------- fused rmsnorm + 3-axis RoPE + scale-fold, bf16 -> bf16 ----------------
__global__ __launch_bounds__(256) void fuse_rms_rope(const ushort* __restrict__ qpre,
                                                     const ushort* __restrict__ kpre,
                                                     const float* __restrict__ gq,
                                                     const float* __restrict__ gk,
                                                     const float* __restrict__ fc,
                                                     const float* __restrict__ fs,
                                                     const int* __restrict__ pH,
                                                     const int* __restrict__ pW,
                                                     ushort* __restrict__ Qb,
                                                     ushort* __restrict__ Kb,
                                                     int dim, float foldq) {
  const int which = blockIdx.y;
  const ushort* pre = which ? kpre : qpre;
  const float* gw = which ? gk : gq;
  ushort* outp = which ? Kb : Qb;
  const float fold = which ? 1.0f : foldq;

  const int p = blockIdx.x, t = threadIdx.x;
  const ushort* row = pre + (size_t)p * dim;
  float v[8];
  {
    uint4 a = *(const uint4*)(row + t * 8);   // 8 bf16
    v[0] = __uint_as_float(a.x << 16); v[1] = __uint_as_float(a.x & 0xffff0000u);
    v[2] = __uint_as_float(a.y << 16); v[3] = __uint_as_float(a.y & 0xffff0000u);
    v[4] = __uint_as_float(a.z << 16); v[5] = __uint_as_float(a.z & 0xffff0000u);
    v[6] = __uint_as_float(a.w << 16); v[7] = __uint_as_float(a.w & 0xffff0000u);
  }
  float ss = 0.f;
#pragma unroll
  for (int i = 0; i < 8; ++i) ss += v[i] * v[i];
#pragma unroll
  for (int off = 32; off; off >>= 1) ss += __shfl_xor(ss, off);
  __shared__ float wsum[4];
  if ((t & 63) == 0) wsum[t >> 6] = ss;
  __syncthreads();
  float rstd = rsqrtf((wsum[0] + wsum[1] + wsum[2] + wsum[3]) * (1.0f / dim) + 1e-6f);
  float gv[8];
  {
    float4 a = *(const float4*)(gw + t * 8);
    float4 b = *(const float4*)(gw + t * 8 + 4);
    gv[0] = a.x; gv[1] = a.y; gv[2] = a.z; gv[3] = a.w;
    gv[4] = b.x; gv[5] = b.y; gv[6] = b.z; gv[7] = b.w;
  }
#pragma unroll
  for (int i = 0; i < 8; ++i) v[i] = v[i] * rstd * gv[i];

  const int H = pH[0], W = pW[0];
  const int hw = H * W;
  const int fr = p / hw;
  const int rem = p - fr * hw;
  const int hh = rem / W;
  const int ww = rem - hh * W;
  const int hd = dim / 16;
  const int cd = hd >> 1;
  const int c2 = cd / 3, c1 = cd - 2 * c2;
  const int j0 = ((t * 8) % hd) >> 1;

  uint ob[4];
#pragma unroll
  for (int q = 0; q < 4; ++q) {
    int j = j0 + q;
    int ri = (j < c1) ? fr : ((j < c1 + c2) ? hh : ww);
    float cs = fc[ri * cd + j];
    float sn = fs[ri * cd + j];
    float a = v[2 * q], b = v[2 * q + 1];
    ob[q] = pack2((a * cs - b * sn) * fold, (a * sn + b * cs) * fold);
  }
  uint4 o4; o4.x = ob[0]; o4.y = ob[1]; o4.z = ob[2]; o4.w = ob[3];
  *(uint4*)(outp + (size_t)p * dim + t * 8) = o4;
}

// ---------------- flash attention, 32x32 MFMA, 4 q-subtiles x 2 KV-splits ----------------
// (R13/R14 proven config: T14 async-STAGE split with NAMED registers, full KV per block)
__global__ __launch_bounds__(512, 2) void attn32(const ushort* __restrict__ Qb,
                                                 const ushort* __restrict__ Kb,
                                                 const ushort* __restrict__ Vt,
                                                 ushort* __restrict__ Ob,
                                                 const int* __restrict__ seq_lens,
                                                 int S_, int DIMc) {
  __shared__ __align__(16) unsigned char smem[66560];
  float* mlbuf = (float*)(smem + 65536);
  const int t = threadIdx.x, l = t & 63, w = t >> 6;
  const int qsub = w & 3, ksp = w >> 2;
  const int h = l >> 5, ql = l & 31;

  const int orig = blockIdx.y * gridDim.x + blockIdx.x;
  const int nwg = gridDim.x * gridDim.y;
  const int lin = (orig & 7) * (nwg >> 3) + (orig >> 3);
  const int q0 = (lin % gridDim.x) * 128;
  const int head = lin / gridDim.x;
  const int kvlen = seq_lens[0];

  unsigned char* sk_s = smem + ksp * 16384;
  unsigned char* sv_s = smem + 32768 + ksp * 16384;

  bf16x8 qf[8];
  {
    const ushort* qp = Qb + (size_t)(q0 + qsub * 32 + ql) * DIMc + head * 128 + h * 8;
#pragma unroll
    for (int s = 0; s < 8; ++s) qf[s] = *(const bf16x8*)(qp + s * 16);
  }

  f32x16 ofr[4] = {};
  float m_run = -1e30f, l_run = 0.f;

  const int nt = (kvlen + 63) >> 6;
  const int half = (nt + 1) >> 1;
  const int tbase = ksp ? half : 0;
  const int mycnt = ksp ? (nt - half) : half;

  // staging invariants — ALL NAMED SCALARS (no arrays -> no scratch, rule #20)
#define MKK(IT, KO, KD) size_t KO; uint KD;                                     \
  { int kr_ = qsub * 16 + (IT) * 4 + (l >> 4); int kc_ = (l & 15) ^ (kr_ & 15); \
    KO = (size_t)kr_ * DIMc + head * 128 + kc_ * 8;                             \
    KD = (uint)(ksp * 16384 + qsub * 4096 + (IT) * 1024 + l * 16); }
#define MKV(IT, VO, VD) size_t VO; uint VD;                                     \
  { int vr_ = qsub * 32 + (IT) * 8 + (l >> 3); int vc_ = (l & 7) ^ (vr_ & 7);   \
    VO = (size_t)(head * 128 + vr_) * S_ + vc_ * 8;                             \
    VD = (uint)(32768 + ksp * 16384 + qsub * 4096 + (IT) * 1024 + l * 16); }
  MKK(0, kO0, kD0) MKK(1, kO1, kD1) MKK(2, kO2, kD2) MKK(3, kO3, kD3)
  MKV(0, vO0, vD0) MKV(1, vO1, vD1) MKV(2, vO2, vD2) MKV(3, vO3, vD3)
#undef MKK
#undef MKV

  uint4 rk0, rk1, rk2, rk3, rv0, rv1, rv2, rv3;
  if (mycnt > 0) {
    const size_t kbq = (size_t)(tbase * 64) * DIMc;
    const int vq = tbase * 64;
    rk0 = *(const uint4*)(Kb + kO0 + kbq);
    rk1 = *(const uint4*)(Kb + kO1 + kbq);
    rk2 = *(const uint4*)(Kb + kO2 + kbq);
    rk3 = *(const uint4*)(Kb + kO3 + kbq);
    rv0 = *(const uint4*)(Vt + vO0 + vq);
    rv1 = *(const uint4*)(Vt + vO1 + vq);
    rv2 = *(const uint4*)(Vt + vO2 + vq);
    rv3 = *(const uint4*)(Vt + vO3 + vq);
  }

  for (int tt = 0; tt < half; ++tt) {
    __builtin_amdgcn_s_barrier();            // prev compute done -> LDS free
    if (tt < mycnt) {
      *(uint4*)(smem + kD0) = rk0; *(uint4*)(smem + kD1) = rk1;
      *(uint4*)(smem + kD2) = rk2; *(uint4*)(smem + kD3) = rk3;
      *(uint4*)(smem + vD0) = rv0; *(uint4*)(smem + vD1) = rv1;
      *(uint4*)(smem + vD2) = rv2; *(uint4*)(smem + vD3) = rv3;
      if (tt + 1 < mycnt) {
        const size_t kbq = (size_t)((tbase + tt + 1) * 64) * DIMc;
        const int vq = (tbase + tt + 1) * 64;
        rk0 = *(const uint4*)(Kb + kO0 + kbq);
        rk1 = *(const uint4*)(Kb + kO1 + kbq);
        rk2 = *(const uint4*)(Kb + kO2 + kbq);
        rk3 = *(const uint4*)(Kb + kO3 + kbq);
        rv0 = *(const uint4*)(Vt + vO0 + vq);
        rv1 = *(const uint4*)(Vt + vO1 + vq);
        rv2 = *(const uint4*)(Vt + vO2 + vq);
        rv3 = *(const uint4*)(Vt + vO3 + vq);
      }
    }
    asm volatile("s_waitcnt lgkmcnt(0)" ::: "memory");   // my ds_writes done
    __builtin_amdgcn_s_barrier();                        // all writes visible
    __builtin_amdgcn_sched_barrier(0);                   // rule #18 fence
    if (tt >= mycnt) continue;
    const int kv0 = (tbase + tt) * 64;

    f32x16 sfr[2] = {};
    __builtin_amdgcn_s_setprio(1);
#pragma unroll
    for (int kb = 0; kb < 2; ++kb) {
      const unsigned char* kbp = sk_s + (kb * 32 + ql) * 256;
      const int rx = (kb * 32 + ql) & 15;
#pragma unroll
      for (int s = 0; s < 8; ++s) {
        bf16x8 kf = *(const bf16x8*)(kbp + (((s * 2 + h) ^ rx) << 4));
        sfr[kb] = __builtin_amdgcn_mfma_f32_32x32x16_bf16(kf, qf[s], sfr[kb], 0, 0, 0);
      }
    }
    __builtin_amdgcn_s_setprio(0);

    if (kv0 + 64 > kvlen) {
#pragma unroll
      for (int kb = 0; kb < 2; ++kb)
#pragma unroll
        for (int r = 0; r < 16; ++r) {
          int key = kv0 + kb * 32 + (r & 3) + 8 * (r >> 2) + 4 * h;
          if (key >= kvlen) sfr[kb][r] = -1e30f;
        }
    }

    float mt = -1e30f;
#pragma unroll
    for (int kb = 0; kb < 2; ++kb)
#pragma unroll
      for (int r = 0; r < 16; ++r) mt = fmaxf(mt, sfr[kb][r]);
    mt = fmaxf(mt, __shfl_xor(mt, 32));

    if (!__all(mt <= m_run + 8.0f)) {
      float m_new = fmaxf(m_run, mt);
      float fac = __builtin_amdgcn_exp2f(m_run - m_new);
      l_run *= fac;
#pragma unroll
      for (int df = 0; df < 4; ++df) ofr[df] *= fac;
      m_run = m_new;
    }

    float ls = 0.f;
    uint u[2][4][2];
#pragma unroll
    for (int kb = 0; kb < 2; ++kb)
#pragma unroll
      for (int G = 0; G < 4; ++G) {
        float p0 = __builtin_amdgcn_exp2f(sfr[kb][G * 4 + 0] - m_run);
        float p1 = __builtin_amdgcn_exp2f(sfr[kb][G * 4 + 1] - m_run);
        float p2 = __builtin_amdgcn_exp2f(sfr[kb][G * 4 + 2] - m_run);
        float p3 = __builtin_amdgcn_exp2f(sfr[kb][G * 4 + 3] - m_run);
        ls += (p0 + p1) + (p2 + p3);
        u[kb][G][0] = cvt_pk_bf16(p0, p1);
        u[kb][G][1] = cvt_pk_bf16(p2, p3);
      }
    ls += __shfl_xor(ls, 32);
    l_run += ls;

#pragma unroll
    for (int ks = 0; ks < 4; ++ks) {
      const int kb = ks >> 1, G0 = (ks & 1) * 2;
      uint own0 = h ? u[kb][G0 + 1][0] : u[kb][G0][0];
      uint own1 = h ? u[kb][G0 + 1][1] : u[kb][G0][1];
      uint snd0 = h ? u[kb][G0][0] : u[kb][G0 + 1][0];
      uint snd1 = h ? u[kb][G0][1] : u[kb][G0 + 1][1];
      uint rcv0 = __shfl_xor(snd0, 32);
      uint rcv1 = __shfl_xor(snd1, 32);
      union { uint4 q; bf16x8 b; } uu;
      uu.q.x = h ? rcv0 : own0;
      uu.q.y = h ? rcv1 : own1;
      uu.q.z = h ? own0 : rcv0;
      uu.q.w = h ? own1 : rcv1;
      __builtin_amdgcn_s_setprio(1);
#pragma unroll
      for (int df = 0; df < 4; ++df) {
        const int row = df * 32 + ql;
        bf16x8 vf = *(const bf16x8*)(sv_s + row * 128 + (((ks * 2 + h) ^ (row & 7)) << 4));
        ofr[df] = __builtin_amdgcn_mfma_f32_32x32x16_bf16(vf, uu.b, ofr[df], 0, 0, 0);
      }
      __builtin_amdgcn_s_setprio(0);
    }
  }

  __syncthreads();
  if (ksp == 1) {
    if (h == 0) { mlbuf[qsub * 64 + ql] = m_run; mlbuf[qsub * 64 + 32 + ql] = l_run; }
    float* ob = (float*)(smem + qsub * 16384);
#pragma unroll
    for (int df = 0; df < 4; ++df)
#pragma unroll
      for (int r = 0; r < 16; ++r) {
        int d = df * 32 + (r & 3) + 8 * (r >> 2) + 4 * h;
        ob[d * 32 + ql] = ofr[df][r];
      }
  }
  __syncthreads();
  if (ksp == 0) {
    float m2 = mlbuf[qsub * 64 + ql], l2 = mlbuf[qsub * 64 + 32 + ql];
    float mstar = fmaxf(m_run, m2);
    float f1 = __builtin_amdgcn_exp2f(m_run - mstar);
    float f2 = (l2 > 0.f) ? __builtin_amdgcn_exp2f(m2 - mstar) : 0.f;
    float lstar = l_run * f1 + l2 * f2;
    float inv = 1.0f / lstar;
    float a1 = f1 * inv, a2 = f2 * inv;
    const float* ob = (const float*)(smem + qsub * 16384);
    ushort* orow = Ob + (size_t)(q0 + qsub * 32 + ql) * DIMc + head * 128;
#pragma unroll
    for (int df = 0; df < 4; ++df)
#pragma unroll
      for (int G = 0; G < 4; ++G) {
        int d0 = df * 32 + 8 * G + 4 * h;
        float v0 = ofr[df][G * 4 + 0] * a1 + ob[(d0 + 0) * 32 + ql] * a2;
        float v1 = ofr[df][G * 4 + 1] * a1 + ob[(d0 + 1) * 32 + ql] * a2;
        float v2 = ofr[df][G * 4 + 2] * a1 + ob[(d0 + 2) * 32 + ql] * a2;
        float v3 = ofr[df][G * 4 + 3] * a1 + ob[(d0 + 3) * 32 + ql] * a2;
        uint2 o; o.x = pack2(v0, v1); o.y = pack2(v2, v3);
        *(uint2*)(orow + d0) = o;
      }
  }
}

// ---------------- host ----------------
extern "C" void kernel_launch(void* const* d_in, const int* in_sizes, int n_in,
                              void* d_out, int out_size, void* d_ws, size_t ws_size,
                              hipStream_t stream) {
  const float* x  = (const float*)d_in[0];
  const float* fc = (const float*)d_in[1];
  const float* fs = (const float*)d_in[2];
  const float* Wq = (const float*)d_in[3];
  const float* bq = (const float*)d_in[4];
  const float* Wk = (const float*)d_in[5];
  const float* bk = (const float*)d_in[6];
  const float* Wv = (const float*)d_in[7];
  const float* bv = (const float*)d_in[8];
  const float* Wo = (const float*)d_in[9];
  const float* bo = (const float*)d_in[10];
  const float* gq = (const float*)d_in[11];
  const float* gk = (const float*)d_in[12];
  const int* seq  = (const int*)d_in[13];
  const int* pH   = (const int*)d_in[15];
  const int* pW   = (const int*)d_in[16];

  const int DIMc = in_sizes[4];          // 2048
  const int S_   = in_sizes[0] / DIMc;   // 2048

  char* ws = (char*)d_ws;
  const size_t MB = 1024ull * 1024ull;
  ushort* xb    = (ushort*)(ws + 0 * MB);
  ushort* Wqkvb = (ushort*)(ws + 8 * MB);    // [6144][2048] bf16 = 24 MB
  ushort* Wob   = (ushort*)(ws + 32 * MB);
  ushort* qpre  = (ushort*)(ws + 40 * MB);   // 8 MB bf16
  ushort* kpre  = (ushort*)(ws + 48 * MB);   // 8 MB bf16
  ushort* Ob    = (ushort*)(ws + 56 * MB);   // 8 MB
  ushort* Qb    = (ushort*)(ws + 72 * MB);
  ushort* Kb    = (ushort*)(ws + 80 * MB);
  ushort* Vt    = (ushort*)(ws + 88 * MB);

  const int nx8 = (S_ * DIMc) / 8;
  const int nw8 = (DIMc * DIMc) / 8;
  const int nmax = (nx8 > nw8 ? nx8 : nw8);
  cvt5<<<dim3((nmax + 255) / 256, 5), 256, 0, stream>>>(x, Wq, Wk, Wv, Wo,
                                                        xb, Wqkvb, Wob, nx8, nw8);

  gemm_qkv192<<<dim3(3 * DIMc / 192, S_ / 256), 512, 0, stream>>>(
      xb, Wqkvb, bq, bk, bv, qpre, kpre, Vt, DIMc, S_);

  const float foldq = LOG2E / sqrtf((float)(DIMc / 16));
  fuse_rms_rope<<<dim3(S_, 2), 256, 0, stream>>>(qpre, kpre, gq, gk, fc, fs, pH, pW,
                                                 Qb, Kb, DIMc, foldq);

  attn32<<<dim3(S_ / 128, 16), 512, 0, stream>>>(Qb, Kb, Vt, Ob, seq, S_, DIMc);

  gemm_wo8p<<<dim3(DIMc / 128, S_ / 128), 512, 0, stream>>>(Ob, Wob, bo,
                                                            (float*)d_out, DIMc);
}

// Round 20
// 153.576 us; speedup vs baseline: 2.6767x; 1.0006x over previous
//
#include <hip/hip_runtime.h>
#include <cstdint>
#include <cmath>

typedef unsigned int uint;
typedef unsigned short ushort;
typedef __bf16 bf16_t;
typedef bf16_t bf16x8 __attribute__((ext_vector_type(8)));
typedef float f32x4 __attribute__((ext_vector_type(4)));
typedef float f32x16 __attribute__((ext_vector_type(16)));

#define LOG2E 1.44269504088896340736f

__device__ __forceinline__ ushort f2bf(float f) {
  uint x = __float_as_uint(f);
  x += 0x7fffu + ((x >> 16) & 1u);   // RNE to bf16
  return (ushort)(x >> 16);
}
__device__ __forceinline__ uint pack2(float lo, float hi) {
  return (uint)f2bf(lo) | ((uint)f2bf(hi) << 16);
}
__device__ __forceinline__ uint cvt_pk_bf16(float lo, float hi) {
  uint r;
  asm("v_cvt_pk_bf16_f32 %0, %1, %2" : "=v"(r) : "v"(lo), "v"(hi));
  return r;
}

// global -> LDS direct copy, 16B per lane; LDS dest is wave-uniform base + lane*16.
__device__ __forceinline__ void gload_lds16(const void* gsrc, void* ldsdst) {
  typedef const __attribute__((address_space(1))) unsigned int* gp_t;
  typedef __attribute__((address_space(3))) unsigned int* lp_t;
  __builtin_amdgcn_global_load_lds((gp_t)(uintptr_t)gsrc,
                                   (lp_t)(unsigned int)(uintptr_t)ldsdst,
                                   16, 0, 0);
}

// ---------------- fp32 -> bf16 converts: x + 4 weights in ONE launch ----------------
__global__ __launch_bounds__(256) void cvt5(const float* __restrict__ x,
                                            const float* __restrict__ wq,
                                            const float* __restrict__ wk,
                                            const float* __restrict__ wv,
                                            const float* __restrict__ wo,
                                            ushort* __restrict__ xb,
                                            ushort* __restrict__ wqkv,
                                            ushort* __restrict__ wob,
                                            int nx8, int nw8) {
  const int y = blockIdx.y;
  const float* src;
  ushort* dst;
  int n8;
  if (y == 0)      { src = x;  dst = xb;  n8 = nx8; }
  else if (y == 4) { src = wo; dst = wob; n8 = nw8; }
  else {
    src = (y == 1) ? wq : (y == 2) ? wk : wv;
    dst = wqkv + (size_t)(y - 1) * nw8 * 8;
    n8 = nw8;
  }
  int i = blockIdx.x * blockDim.x + threadIdx.x;
  if (i >= n8) return;
  const float4* s4 = (const float4*)src;
  float4 a = s4[i * 2], b = s4[i * 2 + 1];
  uint4 o;
  o.x = pack2(a.x, a.y); o.y = pack2(a.z, a.w);
  o.z = pack2(b.x, b.y); o.w = pack2(b.z, b.w);
  ((uint4*)dst)[i] = o;
}

// ---------------- fused QKV GEMM: 256(M) x 192(N) tile, BK=64, 8-phase schedule ------
// Grid (32,8) = 256 blocks = 1 block/CU; counted vmcnt(6) at P4/P8 (T3+T4+T5).
// q/k pre-activations written as BF16 (halves interchange traffic; fuse rounds anyway).
__global__ __launch_bounds__(512) void gemm_qkv192(const ushort* __restrict__ A,
                                                   const ushort* __restrict__ B,
                                                   const float* __restrict__ bq,
                                                   const float* __restrict__ bk,
                                                   const float* __restrict__ bv,
                                                   ushort* __restrict__ qpre,
                                                   ushort* __restrict__ kpre,
                                                   ushort* __restrict__ Vt,
                                                   int K, int S_) {
  __shared__ __align__(16) unsigned char ldsA[65536];   // [2][256 rows][64] bf16
  __shared__ __align__(16) unsigned char ldsB[49152];   // [2][192 rows][64] bf16
  const int t = threadIdx.x, l = t & 63;
  const int w = t >> 6;
  const int g = l >> 4, c = l & 15;
  const int wr = w >> 2, wc = w & 3;          // 2(M) x 4(N) wave grid
  const int tm = blockIdx.y * 256, tn = blockIdx.x * 192;

  const int srow = t >> 3;                    // 0..63
  const int schunk = (t & 7) ^ (srow & 7);    // pre-swizzled source chunk
  const ushort* Ag = A + (size_t)(tm + srow) * K + schunk * 8;
  const ushort* Bg = B + (size_t)(tn + srow) * K + schunk * 8;
  const size_t rK64 = (size_t)64 * K;

#define STG_A(kt, u) gload_lds16(Ag + (size_t)(u) * rK64 + ((kt) << 6),   \
    ldsA + ((kt)&1) * 32768 + (u) * 8192 + t * 16)
#define STG_B(kt, u) gload_lds16(Bg + (size_t)(u) * rK64 + ((kt) << 6),   \
    ldsB + ((kt)&1) * 24576 + (u) * 8192 + t * 16)

  f32x4 acc[8][3] = {};
  bf16x8 af[2][2], bfr[3][2];
  const int cr = c * 128;
  const int sw0 = ((0 * 4 + g) ^ (c & 7)) << 4;
  const int sw1 = ((1 * 4 + g) ^ (c & 7)) << 4;

#define RDA(d, q) do {                                                               \
    _Pragma("unroll") for (int mm = 0; mm < 2; ++mm) {                               \
      const unsigned char* p_ = ldsA + (d)*32768 + (wr*128 + (q)*32 + mm*16)*128 + cr; \
      af[mm][0] = *(const bf16x8*)(p_ + sw0);                                        \
      af[mm][1] = *(const bf16x8*)(p_ + sw1); }                                      \
  } while (0)
#define RDB(d) do {                                                                 \
    _Pragma("unroll") for (int nn = 0; nn < 3; ++nn) {                              \
      const unsigned char* p_ = ldsB + (d)*24576 + (wc*48 + nn*16)*128 + cr;        \
      bfr[nn][0] = *(const bf16x8*)(p_ + sw0);                                      \
      bfr[nn][1] = *(const bf16x8*)(p_ + sw1); }                                    \
  } while (0)
#define MM(q) do {                                                                  \
    __builtin_amdgcn_s_setprio(1);                                                  \
    _Pragma("unroll") for (int mm = 0; mm < 2; ++mm)                                \
    _Pragma("unroll") for (int nn = 0; nn < 3; ++nn) {                              \
      acc[(q)*2+mm][nn] = __builtin_amdgcn_mfma_f32_16x16x32_bf16(                  \
          af[mm][0], bfr[nn][0], acc[(q)*2+mm][nn], 0, 0, 0);                       \
      acc[(q)*2+mm][nn] = __builtin_amdgcn_mfma_f32_16x16x32_bf16(                  \
          af[mm][1], bfr[nn][1], acc[(q)*2+mm][nn], 0, 0, 0); }                     \
    __builtin_amdgcn_s_setprio(0);                                                  \
  } while (0)
#define BAR() __builtin_amdgcn_s_barrier()

  STG_B(0, 0); STG_B(0, 1); STG_B(0, 2);
  STG_A(0, 0); STG_A(0, 1); STG_A(0, 2); STG_A(0, 3);
  STG_B(1, 0); STG_B(1, 1); STG_B(1, 2);
  STG_A(1, 0); STG_A(1, 1); STG_A(1, 2);
  asm volatile("s_waitcnt vmcnt(6)" ::: "memory");
  BAR();

  const int NITER = K >> 7;   // 16 iterations x 2 K-tiles
  for (int i = 0; i < NITER; ++i) {
    const int k1 = 2 * i + 1, k2 = 2 * i + 2, k3 = 2 * i + 3;
    const bool st = (i + 1 < NITER);
    RDA(0, 0); RDB(0);
    STG_A(k1, 3);
    MM(0); BAR();
    RDA(0, 1);
    if (st) { STG_B(k2, 0); STG_B(k2, 1); }
    MM(1); BAR();
    RDA(0, 2);
    if (st) { STG_B(k2, 2); STG_A(k2, 0); }
    MM(2); BAR();
    RDA(0, 3);
    if (st) { STG_A(k2, 1); STG_A(k2, 2); }
    MM(3);
    if (st) asm volatile("s_waitcnt vmcnt(6)" ::: "memory");
    else    asm volatile("s_waitcnt vmcnt(0)" ::: "memory");
    BAR();
    RDA(1, 0); RDB(1);
    if (st) STG_A(k2, 3);
    MM(0); BAR();
    RDA(1, 1);
    if (st) { STG_B(k3, 0); STG_B(k3, 1); }
    MM(1); BAR();
    RDA(1, 2);
    if (st) { STG_B(k3, 2); STG_A(k3, 0); }
    MM(2); BAR();
    RDA(1, 3);
    if (st) { STG_A(k3, 1); STG_A(k3, 2); }
    MM(3);
    if (st) asm volatile("s_waitcnt vmcnt(6)" ::: "memory");
    else    asm volatile("s_waitcnt vmcnt(0)" ::: "memory");
    BAR();
  }

#undef STG_A
#undef STG_B
#undef RDA
#undef RDB
#undef MM
#undef BAR

#pragma unroll
  for (int n = 0; n < 3; ++n) {
    int col = tn + wc * 48 + n * 16 + c;
    int sel = col >> 11;
    if (sel < 2) {
      ushort* outp = sel ? kpre : qpre;
      const float* bias = sel ? bk : bq;
      int col2 = col & 2047;
      float bvv = bias[col2];
#pragma unroll
      for (int m = 0; m < 8; ++m) {
        int row0 = tm + wr * 128 + m * 16 + g * 4;
#pragma unroll
        for (int i = 0; i < 4; ++i)
          outp[(size_t)(row0 + i) * 2048 + col2] = f2bf(acc[m][n][i] + bvv);
      }
    } else {
      int colv = col - 4096;
      float bvv = bv[colv];
#pragma unroll
      for (int m = 0; m < 8; ++m) {
        int row0 = tm + wr * 128 + m * 16 + g * 4;
        uint2 o;
        o.x = pack2(acc[m][n][0] + bvv, acc[m][n][1] + bvv);
        o.y = pack2(acc[m][n][2] + bvv, acc[m][n][3] + bvv);
        *(uint2*)(Vt + (size_t)colv * S_ + row0) = o;
      }
    }
  }
}

// ---------------- Wo GEMM: single-pass 128x128 tile, BK=64, 4-phase counted pipeline --
__global__ __launch_bounds__(512) void gemm_wo8p(const ushort* __restrict__ A,
                                                 const ushort* __restrict__ B,
                                                 const float* __restrict__ bo,
                                                 float* __restrict__ out, int K) {
  __shared__ __align__(16) unsigned char ldsA[32768];
  __shared__ __align__(16) unsigned char ldsB[32768];
  const int t = threadIdx.x, l = t & 63;
  const int w = t >> 6;
  const int g = l >> 4, c = l & 15;
  const int wr = w >> 2, wc = w & 3;
  const int tm = blockIdx.y * 128, tn = blockIdx.x * 128;

  const int srow = t >> 3;
  const int schunk = (t & 7) ^ (srow & 7);
  const ushort* Ag = A + (size_t)(tm + srow) * K + schunk * 8;
  const ushort* Bg = B + (size_t)(tn + srow) * K + schunk * 8;
  const size_t rK64 = (size_t)64 * K;

#define WSTG_A(kt, u) gload_lds16(Ag + (size_t)(u) * rK64 + ((kt) << 6),   \
    ldsA + ((kt)&1) * 16384 + (u) * 8192 + t * 16)
#define WSTG_B(kt, u) gload_lds16(Bg + (size_t)(u) * rK64 + ((kt) << 6),   \
    ldsB + ((kt)&1) * 16384 + (u) * 8192 + t * 16)

  f32x4 acc[4][2] = {};
  bf16x8 af[2][2], bfr[2][2];
  const int cr = c * 128;
  const int sw0 = ((0 * 4 + g) ^ (c & 7)) << 4;
  const int sw1 = ((1 * 4 + g) ^ (c & 7)) << 4;

#define WRDA(d, hf) do {                                                             \
    _Pragma("unroll") for (int mm = 0; mm < 2; ++mm) {                               \
      const unsigned char* p_ = ldsA + (d)*16384 + (wr*64 + ((hf)*2+mm)*16)*128 + cr; \
      af[mm][0] = *(const bf16x8*)(p_ + sw0);                                        \
      af[mm][1] = *(const bf16x8*)(p_ + sw1); }                                      \
  } while (0)
#define WRDB(d) do {                                                                \
    _Pragma("unroll") for (int nn = 0; nn < 2; ++nn) {                              \
      const unsigned char* p_ = ldsB + (d)*16384 + (wc*32 + nn*16)*128 + cr;        \
      bfr[nn][0] = *(const bf16x8*)(p_ + sw0);                                      \
      bfr[nn][1] = *(const bf16x8*)(p_ + sw1); }                                    \
  } while (0)
#define WMM(hf) do {                                                                \
    __builtin_amdgcn_s_setprio(1);                                                  \
    _Pragma("unroll") for (int mm = 0; mm < 2; ++mm)                                \
    _Pragma("unroll") for (int nn = 0; nn < 2; ++nn) {                              \
      acc[(hf)*2+mm][nn] = __builtin_amdgcn_mfma_f32_16x16x32_bf16(                 \
          af[mm][0], bfr[nn][0], acc[(hf)*2+mm][nn], 0, 0, 0);                      \
      acc[(hf)*2+mm][nn] = __builtin_amdgcn_mfma_f32_16x16x32_bf16(                 \
          af[mm][1], bfr[nn][1], acc[(hf)*2+mm][nn], 0, 0, 0); }                    \
    __builtin_amdgcn_s_setprio(0);                                                  \
  } while (0)
#define WBAR() __builtin_amdgcn_s_barrier()

  WSTG_B(0, 0); WSTG_B(0, 1); WSTG_A(0, 0); WSTG_A(0, 1);
  WSTG_B(1, 0); WSTG_B(1, 1);
  asm volatile("s_waitcnt vmcnt(2)" ::: "memory");
  WBAR();

  const int NITER = K >> 7;
  for (int i = 0; i < NITER; ++i) {
    const int k1 = 2 * i + 1, k2 = 2 * i + 2, k3 = 2 * i + 3;
    const bool st = (i + 1 < NITER);
    WRDA(0, 0); WRDB(0);
    WSTG_A(k1, 0); WSTG_A(k1, 1);
    WMM(0); WBAR();
    WRDA(0, 1);
    if (st) { WSTG_B(k2, 0); WSTG_B(k2, 1); }
    WMM(1);
    if (st) asm volatile("s_waitcnt vmcnt(2)" ::: "memory");
    else    asm volatile("s_waitcnt vmcnt(0)" ::: "memory");
    WBAR();
    WRDA(1, 0); WRDB(1);
    if (st) { WSTG_A(k2, 0); WSTG_A(k2, 1); }
    WMM(0); WBAR();
    WRDA(1, 1);
    if (st) { WSTG_B(k3, 0); WSTG_B(k3, 1); }
    WMM(1);
    if (st) asm volatile("s_waitcnt vmcnt(2)" ::: "memory");
    else    asm volatile("s_waitcnt vmcnt(0)" ::: "memory");
    WBAR();
  }

#undef WSTG_A
#undef WSTG_B
#undef WRDA
#undef WRDB
#undef WMM
#undef WBAR

#pragma unroll
  for (int n = 0; n < 2; ++n) {
    int col = tn + wc * 32 + n * 16 + c;
    float bvv = bo[col];
#pragma unroll
    for (int m = 0; m < 4; ++m) {
      int row0 = tm + wr * 64 + m * 16 + g * 4;
#pragma unroll
      for (int i = 0; i < 4; ++i)
        out[(size_t)(row0 + i) * 2048 + col] = acc[m][n][i] + bvv;
    }
  }
}

// ---------------- fused rmsnorm + 3-axis RoPE + scale-fold, bf16 -> bf16 ----------------
__global__ __launch_bounds__(256) void fuse_rms_rope(const ushort* __restrict__ qpre,
                                                     const ushort* __restrict__ kpre,
                                                     const float* __restrict__ gq,
                                                     const float* __restrict__ gk,
                                                     const float* __restrict__ fc,
                                                     const float* __restrict__ fs,
                                                     const int* __restrict__ pH,
                                                     const int* __restrict__ pW,
                                                     ushort* __restrict__ Qb,
                                                     ushort* __restrict__ Kb,
                                                     int dim, float foldq) {
  const int which = blockIdx.y;
  const ushort* pre = which ? kpre : qpre;
  const float* gw = which ? gk : gq;
  ushort* outp = which ? Kb : Qb;
  const float fold = which ? 1.0f : foldq;

  const int p = blockIdx.x, t = threadIdx.x;
  const ushort* row = pre + (size_t)p * dim;
  float v[8];
  {
    uint4 a = *(const uint4*)(row + t * 8);   // 8 bf16
    v[0] = __uint_as_float(a.x << 16); v[1] = __uint_as_float(a.x & 0xffff0000u);
    v[2] = __uint_as_float(a.y << 16); v[3] = __uint_as_float(a.y & 0xffff0000u);
    v[4] = __uint_as_float(a.z << 16); v[5] = __uint_as_float(a.z & 0xffff0000u);
    v[6] = __uint_as_float(a.w << 16); v[7] = __uint_as_float(a.w & 0xffff0000u);
  }
  float ss = 0.f;
#pragma unroll
  for (int i = 0; i < 8; ++i) ss += v[i] * v[i];
#pragma unroll
  for (int off = 32; off; off >>= 1) ss += __shfl_xor(ss, off);
  __shared__ float wsum[4];
  if ((t & 63) == 0) wsum[t >> 6] = ss;
  __syncthreads();
  float rstd = rsqrtf((wsum[0] + wsum[1] + wsum[2] + wsum[3]) * (1.0f / dim) + 1e-6f);
  float gv[8];
  {
    float4 a = *(const float4*)(gw + t * 8);
    float4 b = *(const float4*)(gw + t * 8 + 4);
    gv[0] = a.x; gv[1] = a.y; gv[2] = a.z; gv[3] = a.w;
    gv[4] = b.x; gv[5] = b.y; gv[6] = b.z; gv[7] = b.w;
  }
#pragma unroll
  for (int i = 0; i < 8; ++i) v[i] = v[i] * rstd * gv[i];

  const int H = pH[0], W = pW[0];
  const int hw = H * W;
  const int fr = p / hw;
  const int rem = p - fr * hw;
  const int hh = rem / W;
  const int ww = rem - hh * W;
  const int hd = dim / 16;
  const int cd = hd >> 1;
  const int c2 = cd / 3, c1 = cd - 2 * c2;
  const int j0 = ((t * 8) % hd) >> 1;

  uint ob[4];
#pragma unroll
  for (int q = 0; q < 4; ++q) {
    int j = j0 + q;
    int ri = (j < c1) ? fr : ((j < c1 + c2) ? hh : ww);
    float cs = fc[ri * cd + j];
    float sn = fs[ri * cd + j];
    float a = v[2 * q], b = v[2 * q + 1];
    ob[q] = pack2((a * cs - b * sn) * fold, (a * sn + b * cs) * fold);
  }
  uint4 o4; o4.x = ob[0]; o4.y = ob[1]; o4.z = ob[2]; o4.w = ob[3];
  *(uint4*)(outp + (size_t)p * dim + t * 8) = o4;
}

// ---------------- flash attention, 32x32 MFMA, 4 q-subtiles x 2 KV-splits ----------------
// (T14 async-STAGE split with NAMED registers, full KV per block — proven config)
__global__ __launch_bounds__(512, 2) void attn32(const ushort* __restrict__ Qb,
                                                 const ushort* __restrict__ Kb,
                                                 const ushort* __restrict__ Vt,
                                                 ushort* __restrict__ Ob,
                                                 const int* __restrict__ seq_lens,
                                                 int S_, int DIMc) {
  __shared__ __align__(16) unsigned char smem[66560];
  float* mlbuf = (float*)(smem + 65536);
  const int t = threadIdx.x, l = t & 63, w = t >> 6;
  const int qsub = w & 3, ksp = w >> 2;
  const int h = l >> 5, ql = l & 31;

  const int orig = blockIdx.y * gridDim.x + blockIdx.x;
  const int nwg = gridDim.x * gridDim.y;
  const int lin = (orig & 7) * (nwg >> 3) + (orig >> 3);
  const int q0 = (lin % gridDim.x) * 128;
  const int head = lin / gridDim.x;
  const int kvlen = seq_lens[0];

  unsigned char* sk_s = smem + ksp * 16384;
  unsigned char* sv_s = smem + 32768 + ksp * 16384;

  bf16x8 qf[8];
  {
    const ushort* qp = Qb + (size_t)(q0 + qsub * 32 + ql) * DIMc + head * 128 + h * 8;
#pragma unroll
    for (int s = 0; s < 8; ++s) qf[s] = *(const bf16x8*)(qp + s * 16);
  }

  f32x16 ofr[4] = {};
  float m_run = -1e30f, l_run = 0.f;

  const int nt = (kvlen + 63) >> 6;
  const int half = (nt + 1) >> 1;
  const int tbase = ksp ? half : 0;
  const int mycnt = ksp ? (nt - half) : half;

  // staging invariants — ALL NAMED SCALARS (no arrays -> no scratch, rule #20)
#define MKK(IT, KO, KD) size_t KO; uint KD;                                     \
  { int kr_ = qsub * 16 + (IT) * 4 + (l >> 4); int kc_ = (l & 15) ^ (kr_ & 15); \
    KO = (size_t)kr_ * DIMc + head * 128 + kc_ * 8;                             \
    KD = (uint)(ksp * 16384 + qsub * 4096 + (IT) * 1024 + l * 16); }
#define MKV(IT, VO, VD) size_t VO; uint VD;                                     \
  { int vr_ = qsub * 32 + (IT) * 8 + (l >> 3); int vc_ = (l & 7) ^ (vr_ & 7);   \
    VO = (size_t)(head * 128 + vr_) * S_ + vc_ * 8;                             \
    VD = (uint)(32768 + ksp * 16384 + qsub * 4096 + (IT) * 1024 + l * 16); }
  MKK(0, kO0, kD0) MKK(1, kO1, kD1) MKK(2, kO2, kD2) MKK(3, kO3, kD3)
  MKV(0, vO0, vD0) MKV(1, vO1, vD1) MKV(2, vO2, vD2) MKV(3, vO3, vD3)
#undef MKK
#undef MKV

  uint4 rk0, rk1, rk2, rk3, rv0, rv1, rv2, rv3;
  if (mycnt > 0) {
    const size_t kbq = (size_t)(tbase * 64) * DIMc;
    const int vq = tbase * 64;
    rk0 = *(const uint4*)(Kb + kO0 + kbq);
    rk1 = *(const uint4*)(Kb + kO1 + kbq);
    rk2 = *(const uint4*)(Kb + kO2 + kbq);
    rk3 = *(const uint4*)(Kb + kO3 + kbq);
    rv0 = *(const uint4*)(Vt + vO0 + vq);
    rv1 = *(const uint4*)(Vt + vO1 + vq);
    rv2 = *(const uint4*)(Vt + vO2 + vq);
    rv3 = *(const uint4*)(Vt + vO3 + vq);
  }

  for (int tt = 0; tt < half; ++tt) {
    __builtin_amdgcn_s_barrier();            // prev compute done -> LDS free
    if (tt < mycnt) {
      *(uint4*)(smem + kD0) = rk0; *(uint4*)(smem + kD1) = rk1;
      *(uint4*)(smem + kD2) = rk2; *(uint4*)(smem + kD3) = rk3;
      *(uint4*)(smem + vD0) = rv0; *(uint4*)(smem + vD1) = rv1;
      *(uint4*)(smem + vD2) = rv2; *(uint4*)(smem + vD3) = rv3;
      if (tt + 1 < mycnt) {
        const size_t kbq = (size_t)((tbase + tt + 1) * 64) * DIMc;
        const int vq = (tbase + tt + 1) * 64;
        rk0 = *(const uint4*)(Kb + kO0 + kbq);
        rk1 = *(const uint4*)(Kb + kO1 + kbq);
        rk2 = *(const uint4*)(Kb + kO2 + kbq);
        rk3 = *(const uint4*)(Kb + kO3 + kbq);
        rv0 = *(const uint4*)(Vt + vO0 + vq);
        rv1 = *(const uint4*)(Vt + vO1 + vq);
        rv2 = *(const uint4*)(Vt + vO2 + vq);
        rv3 = *(const uint4*)(Vt + vO3 + vq);
      }
    }
    asm volatile("s_waitcnt lgkmcnt(0)" ::: "memory");   // my ds_writes done
    __builtin_amdgcn_s_barrier();                        // all writes visible
    __builtin_amdgcn_sched_barrier(0);                   // rule #18 fence
    if (tt >= mycnt) continue;
    const int kv0 = (tbase + tt) * 64;

    f32x16 sfr[2] = {};
    __builtin_amdgcn_s_setprio(1);
#pragma unroll
    for (int kb = 0; kb < 2; ++kb) {
      const unsigned char* kbp = sk_s + (kb * 32 + ql) * 256;
      const int rx = (kb * 32 + ql) & 15;
#pragma unroll
      for (int s = 0; s < 8; ++s) {
        bf16x8 kf = *(const bf16x8*)(kbp + (((s * 2 + h) ^ rx) << 4));
        sfr[kb] = __builtin_amdgcn_mfma_f32_32x32x16_bf16(kf, qf[s], sfr[kb], 0, 0, 0);
      }
    }
    __builtin_amdgcn_s_setprio(0);

    if (kv0 + 64 > kvlen) {
#pragma unroll
      for (int kb = 0; kb < 2; ++kb)
#pragma unroll
        for (int r = 0; r < 16; ++r) {
          int key = kv0 + kb * 32 + (r & 3) + 8 * (r >> 2) + 4 * h;
          if (key >= kvlen) sfr[kb][r] = -1e30f;
        }
    }

    float mt = -1e30f;
#pragma unroll
    for (int kb = 0; kb < 2; ++kb)
#pragma unroll
      for (int r = 0; r < 16; ++r) mt = fmaxf(mt, sfr[kb][r]);
    mt = fmaxf(mt, __shfl_xor(mt, 32));

    if (!__all(mt <= m_run + 8.0f)) {
      float m_new = fmaxf(m_run, mt);
      float fac = __builtin_amdgcn_exp2f(m_run - m_new);
      l_run *= fac;
#pragma unroll
      for (int df = 0; df < 4; ++df) ofr[df] *= fac;
      m_run = m_new;
    }

    float ls = 0.f;
    uint u[2][4][2];
#pragma unroll
    for (int kb = 0; kb < 2; ++kb)
#pragma unroll
      for (int G = 0; G < 4; ++G) {
        float p0 = __builtin_amdgcn_exp2f(sfr[kb][G * 4 + 0] - m_run);
        float p1 = __builtin_amdgcn_exp2f(sfr[kb][G * 4 + 1] - m_run);
        float p2 = __builtin_amdgcn_exp2f(sfr[kb][G * 4 + 2] - m_run);
        float p3 = __builtin_amdgcn_exp2f(sfr[kb][G * 4 + 3] - m_run);
        ls += (p0 + p1) + (p2 + p3);
        u[kb][G][0] = cvt_pk_bf16(p0, p1);
        u[kb][G][1] = cvt_pk_bf16(p2, p3);
      }
    ls += __shfl_xor(ls, 32);
    l_run += ls;

#pragma unroll
    for (int ks = 0; ks < 4; ++ks) {
      const int kb = ks >> 1, G0 = (ks & 1) * 2;
      uint own0 = h ? u[kb][G0 + 1][0] : u[kb][G0][0];
      uint own1 = h ? u[kb][G0 + 1][1] : u[kb][G0][1];
      uint snd0 = h ? u[kb][G0][0] : u[kb][G0 + 1][0];
      uint snd1 = h ? u[kb][G0][1] : u[kb][G0 + 1][1];
      uint rcv0 = __shfl_xor(snd0, 32);
      uint rcv1 = __shfl_xor(snd1, 32);
      union { uint4 q; bf16x8 b; } uu;
      uu.q.x = h ? rcv0 : own0;
      uu.q.y = h ? rcv1 : own1;
      uu.q.z = h ? own0 : rcv0;
      uu.q.w = h ? own1 : rcv1;
      __builtin_amdgcn_s_setprio(1);
#pragma unroll
      for (int df = 0; df < 4; ++df) {
        const int row = df * 32 + ql;
        bf16x8 vf = *(const bf16x8*)(sv_s + row * 128 + (((ks * 2 + h) ^ (row & 7)) << 4));
        ofr[df] = __builtin_amdgcn_mfma_f32_32x32x16_bf16(vf, uu.b, ofr[df], 0, 0, 0);
      }
      __builtin_amdgcn_s_setprio(0);
    }
  }

  __syncthreads();
  if (ksp == 1) {
    if (h == 0) { mlbuf[qsub * 64 + ql] = m_run; mlbuf[qsub * 64 + 32 + ql] = l_run; }
    float* ob = (float*)(smem + qsub * 16384);
#pragma unroll
    for (int df = 0; df < 4; ++df)
#pragma unroll
      for (int r = 0; r < 16; ++r) {
        int d = df * 32 + (r & 3) + 8 * (r >> 2) + 4 * h;
        ob[d * 32 + ql] = ofr[df][r];
      }
  }
  __syncthreads();
  if (ksp == 0) {
    float m2 = mlbuf[qsub * 64 + ql], l2 = mlbuf[qsub * 64 + 32 + ql];
    float mstar = fmaxf(m_run, m2);
    float f1 = __builtin_amdgcn_exp2f(m_run - mstar);
    float f2 = (l2 > 0.f) ? __builtin_amdgcn_exp2f(m2 - mstar) : 0.f;
    float lstar = l_run * f1 + l2 * f2;
    float inv = 1.0f / lstar;
    float a1 = f1 * inv, a2 = f2 * inv;
    const float* ob = (const float*)(smem + qsub * 16384);
    ushort* orow = Ob + (size_t)(q0 + qsub * 32 + ql) * DIMc + head * 128;
#pragma unroll
    for (int df = 0; df < 4; ++df)
#pragma unroll
      for (int G = 0; G < 4; ++G) {
        int d0 = df * 32 + 8 * G + 4 * h;
        float v0 = ofr[df][G * 4 + 0] * a1 + ob[(d0 + 0) * 32 + ql] * a2;
        float v1 = ofr[df][G * 4 + 1] * a1 + ob[(d0 + 1) * 32 + ql] * a2;
        float v2 = ofr[df][G * 4 + 2] * a1 + ob[(d0 + 2) * 32 + ql] * a2;
        float v3 = ofr[df][G * 4 + 3] * a1 + ob[(d0 + 3) * 32 + ql] * a2;
        uint2 o; o.x = pack2(v0, v1); o.y = pack2(v2, v3);
        *(uint2*)(orow + d0) = o;
      }
  }
}

// ---------------- host ----------------
extern "C" void kernel_launch(void* const* d_in, const int* in_sizes, int n_in,
                              void* d_out, int out_size, void* d_ws, size_t ws_size,
                              hipStream_t stream) {
  const float* x  = (const float*)d_in[0];
  const float* fc = (const float*)d_in[1];
  const float* fs = (const float*)d_in[2];
  const float* Wq = (const float*)d_in[3];
  const float* bq = (const float*)d_in[4];
  const float* Wk = (const float*)d_in[5];
  const float* bk = (const float*)d_in[6];
  const float* Wv = (const float*)d_in[7];
  const float* bv = (const float*)d_in[8];
  const float* Wo = (const float*)d_in[9];
  const float* bo = (const float*)d_in[10];
  const float* gq = (const float*)d_in[11];
  const float* gk = (const float*)d_in[12];
  const int* seq  = (const int*)d_in[13];
  const int* pH   = (const int*)d_in[15];
  const int* pW   = (const int*)d_in[16];

  const int DIMc = in_sizes[4];          // 2048
  const int S_   = in_sizes[0] / DIMc;   // 2048

  char* ws = (char*)d_ws;
  const size_t MB = 1024ull * 1024ull;
  ushort* xb    = (ushort*)(ws + 0 * MB);
  ushort* Wqkvb = (ushort*)(ws + 8 * MB);    // [6144][2048] bf16 = 24 MB
  ushort* Wob   = (ushort*)(ws + 32 * MB);
  ushort* qpre  = (ushort*)(ws + 40 * MB);   // 8 MB bf16
  ushort* kpre  = (ushort*)(ws + 48 * MB);   // 8 MB bf16
  ushort* Ob    = (ushort*)(ws + 56 * MB);   // 8 MB
  ushort* Qb    = (ushort*)(ws + 72 * MB);
  ushort* Kb    = (ushort*)(ws + 80 * MB);
  ushort* Vt    = (ushort*)(ws + 88 * MB);

  const int nx8 = (S_ * DIMc) / 8;
  const int nw8 = (DIMc * DIMc) / 8;
  const int nmax = (nx8 > nw8 ? nx8 : nw8);
  cvt5<<<dim3((nmax + 255) / 256, 5), 256, 0, stream>>>(x, Wq, Wk, Wv, Wo,
                                                        xb, Wqkvb, Wob, nx8, nw8);

  gemm_qkv192<<<dim3(3 * DIMc / 192, S_ / 256), 512, 0, stream>>>(
      xb, Wqkvb, bq, bk, bv, qpre, kpre, Vt, DIMc, S_);

  const float foldq = LOG2E / sqrtf((float)(DIMc / 16));
  fuse_rms_rope<<<dim3(S_, 2), 256, 0, stream>>>(qpre, kpre, gq, gk, fc, fs, pH, pW,
                                                 Qb, Kb, DIMc, foldq);

  attn32<<<dim3(S_ / 128, 16), 512, 0, stream>>>(Qb, Kb, Vt, Ob, seq, S_, DIMc);

  gemm_wo8p<<<dim3(DIMc / 128, S_ / 128), 512, 0, stream>>>(Ob, Wob, bo,
                                                            (float*)d_out, DIMc);
}